// Round 9
// baseline (2081.576 us; speedup 1.0000x reference)
//
#include <hip/hip_runtime.h>

// ---------------------------------------------------------------------------
// PIGNN round 5: direct global->register MFMA fragment loads (no A/B LDS
// staging, 3 barriers/block, 4 blocks/CU), LDS only for hidden exchange.
// Edges counting-sorted by dst; segmented-reduce scatter (round 4).
// Tier 3: full path. Tier 2/1/0: earlier fallbacks.
// ---------------------------------------------------------------------------

#define TILE 32   // rows per block for the f32 VALU kernels

typedef unsigned short u16;
typedef u16   ushort8 __attribute__((ext_vector_type(8)));
typedef __bf16 bf16x8 __attribute__((ext_vector_type(8)));
typedef float f32x16  __attribute__((ext_vector_type(16)));

__device__ __forceinline__ unsigned f2bf(float f) {      // RNE f32->bf16 (low 16)
    unsigned u = __float_as_uint(f);
    return (u + 0x7fffu + ((u >> 16) & 1u)) >> 16;
}
__device__ __forceinline__ float bf2f(unsigned s) {       // bf16(low16)->f32
    return __uint_as_float(s << 16);
}

// ----------------- f32 register-tile GEMM helper (VALU path) ---------------
template<int K, int KP, int NOUT>
__device__ __forceinline__ void gemm_tile_phase(const float* in_lds,
                                                const float* __restrict__ W,
                                                const float* __restrict__ b,
                                                float acc[4][4], int jq, int rg) {
    #pragma unroll
    for (int c = 0; c < 4; ++c) {
        float bv = b[jq + c];
        acc[0][c] = bv; acc[1][c] = bv; acc[2][c] = bv; acc[3][c] = bv;
    }
    int k = 0;
    for (; k + 4 <= K; k += 4) {
        float4 w0 = *(const float4*)&W[(k + 0) * NOUT + jq];
        float4 w1 = *(const float4*)&W[(k + 1) * NOUT + jq];
        float4 w2 = *(const float4*)&W[(k + 2) * NOUT + jq];
        float4 w3 = *(const float4*)&W[(k + 3) * NOUT + jq];
        #pragma unroll
        for (int rr = 0; rr < 4; ++rr) {
            int row = rg + rr * 8;
            float4 xv = *(const float4*)&in_lds[row * KP + k];
            acc[rr][0] += xv.x * w0.x + xv.y * w1.x + xv.z * w2.x + xv.w * w3.x;
            acc[rr][1] += xv.x * w0.y + xv.y * w1.y + xv.z * w2.y + xv.w * w3.y;
            acc[rr][2] += xv.x * w0.z + xv.y * w1.z + xv.z * w2.z + xv.w * w3.z;
            acc[rr][3] += xv.x * w0.w + xv.y * w1.w + xv.z * w2.w + xv.w * w3.w;
        }
    }
    for (; k < K; ++k) {
        float4 w0 = *(const float4*)&W[k * NOUT + jq];
        #pragma unroll
        for (int rr = 0; rr < 4; ++rr) {
            float xv = in_lds[(rg + rr * 8) * KP + k];
            acc[rr][0] += xv * w0.x;
            acc[rr][1] += xv * w0.y;
            acc[rr][2] += xv * w0.z;
            acc[rr][3] += xv * w0.w;
        }
    }
}

__device__ __forceinline__ float4 relu4(const float a[4]) {
    return make_float4(fmaxf(a[0], 0.f), fmaxf(a[1], 0.f),
                       fmaxf(a[2], 0.f), fmaxf(a[3], 0.f));
}

// ----------------------------- node encoder -------------------------------
__global__ __launch_bounds__(256) void node_enc_kernel(
    const float* __restrict__ x, const float* __restrict__ coords,
    const float* __restrict__ W1, const float* __restrict__ b1,
    const float* __restrict__ W2, const float* __restrict__ b2,
    float* __restrict__ h, u16* __restrict__ h_bf, int N_) {
    __shared__ float in9[TILE * 12];
    __shared__ float hid[TILE * 128];
    int t = threadIdx.x;
    int n0 = blockIdx.x * TILE;
    for (int i = t; i < TILE * 12; i += 256) {
        int r = i / 12, k = i % 12;
        int n = min(n0 + r, N_ - 1);
        float v = 0.f;
        if (k < 3) v = coords[n * 3 + k];
        else if (k < 9) v = x[n * 9 + k];
        in9[i] = v;
    }
    __syncthreads();
    int jq = (t & 31) * 4, rg = t >> 5;
    float acc[4][4];
    gemm_tile_phase<9, 12, 128>(in9, W1, b1, acc, jq, rg);
    #pragma unroll
    for (int rr = 0; rr < 4; ++rr)
        *(float4*)&hid[(rg + rr * 8) * 128 + jq] = relu4(acc[rr]);
    __syncthreads();
    gemm_tile_phase<128, 128, 128>(hid, W2, b2, acc, jq, rg);
    #pragma unroll
    for (int rr = 0; rr < 4; ++rr) {
        int n = n0 + rg + rr * 8;
        if (n < N_) {
            *(float4*)&h[(size_t)n * 128 + jq] =
                make_float4(acc[rr][0], acc[rr][1], acc[rr][2], acc[rr][3]);
            if (h_bf) {
                unsigned p0 = f2bf(acc[rr][0]) | (f2bf(acc[rr][1]) << 16);
                unsigned p1 = f2bf(acc[rr][2]) | (f2bf(acc[rr][3]) << 16);
                *(uint2*)&h_bf[(size_t)n * 128 + jq] = make_uint2(p0, p1);
            }
        }
    }
}

// ------------------- edge encoder (f32 VALU, bf16 out; tier<=2) ------------
__global__ __launch_bounds__(256) void edge_enc_bf16_kernel(
    const float* __restrict__ ea,
    const float* __restrict__ W1, const float* __restrict__ b1,
    const float* __restrict__ W2, const float* __restrict__ b2,
    u16* __restrict__ e, int E_) {
    __shared__ float in10[TILE * 12];
    __shared__ float hid[TILE * 128];
    int t = threadIdx.x;
    int e0 = blockIdx.x * TILE;
    for (int i = t; i < TILE * 12; i += 256) {
        int r = i / 12, k = i % 12;
        int eg = min(e0 + r, E_ - 1);
        in10[i] = (k < 10) ? ea[(size_t)eg * 10 + k] : 0.f;
    }
    __syncthreads();
    int jq = (t & 31) * 4, rg = t >> 5;
    float acc[4][4];
    gemm_tile_phase<10, 12, 128>(in10, W1, b1, acc, jq, rg);
    #pragma unroll
    for (int rr = 0; rr < 4; ++rr)
        *(float4*)&hid[(rg + rr * 8) * 128 + jq] = relu4(acc[rr]);
    __syncthreads();
    gemm_tile_phase<128, 128, 128>(hid, W2, b2, acc, jq, rg);
    #pragma unroll
    for (int rr = 0; rr < 4; ++rr) {
        int eg = e0 + rg + rr * 8;
        if (eg < E_) {
            unsigned p0 = f2bf(acc[rr][0]) | (f2bf(acc[rr][1]) << 16);
            unsigned p1 = f2bf(acc[rr][2]) | (f2bf(acc[rr][3]) << 16);
            *(uint2*)&e[(size_t)eg * 128 + jq] = make_uint2(p0, p1);
        }
    }
}

// ---------- weight prep: f32 stacked [L][K][N] -> bf16^T [L][N][Kp] --------
__global__ __launch_bounds__(256) void wt_stacked_kernel(
    const float* __restrict__ W, u16* __restrict__ Wt,
    int Lc, int K, int Kp, int Nn) {
    size_t i = (size_t)blockIdx.x * 256 + threadIdx.x;
    size_t tot = (size_t)Lc * Nn * Kp;
    if (i >= tot) return;
    int k = (int)(i % Kp);
    size_t r = i / Kp;
    int n = (int)(r % Nn);
    int l = (int)(r / Nn);
    Wt[i] = (k < K) ? (u16)f2bf(W[((size_t)l * K + k) * Nn + n]) : (u16)0;
}

// --------------------------- counting sort by dst --------------------------
__global__ __launch_bounds__(256) void hist_kernel(
    const int* __restrict__ dst, int* __restrict__ cnt, int E_) {
    int i = blockIdx.x * 256 + threadIdx.x;
    if (i < E_) atomicAdd(&cnt[dst[i]], 1);
}

__global__ __launch_bounds__(1024) void scan_kernel(
    const int* __restrict__ cnt, int* __restrict__ row_ptr, int n) {
    __shared__ int sums[1024];
    int t = threadIdx.x;
    int per = (n + 1023) / 1024;
    int lo = t * per, hi = min(lo + per, n);
    int s = 0;
    for (int i = lo; i < hi; ++i) s += cnt[i];
    sums[t] = s;
    __syncthreads();
    for (int d = 1; d < 1024; d <<= 1) {
        int v = (t >= d) ? sums[t - d] : 0;
        __syncthreads();
        sums[t] += v;
        __syncthreads();
    }
    int run = sums[t] - s;   // exclusive prefix of this chunk
    for (int i = lo; i < hi; ++i) { row_ptr[i] = run; run += cnt[i]; }
    if (t == 1023) row_ptr[n] = run;
}

__global__ __launch_bounds__(256) void scatter_kernel(
    const int* __restrict__ src, const int* __restrict__ dst,
    const int* __restrict__ row_ptr, int* __restrict__ fill,
    int* __restrict__ src_s, int* __restrict__ dst_s, int* __restrict__ permE,
    int E_) {
    int i = blockIdx.x * 256 + threadIdx.x;
    if (i >= E_) return;
    int d = dst[i];
    int pos = row_ptr[d] + atomicAdd(&fill[d], 1);
    src_s[pos] = src[i];
    dst_s[pos] = d;
    permE[pos] = i;
}

// ------------------- edge encoder (bf16 MFMA, tier 3) ----------------------
__global__ __launch_bounds__(256) void edge_enc_mfma_kernel(
    const float* __restrict__ ea,
    const u16* __restrict__ W1t,   // [128][16], k-padded
    const float* __restrict__ b1,
    const u16* __restrict__ W2t,   // [128][128]
    const float* __restrict__ b2,
    u16* __restrict__ e_bf, int E_) {
    __shared__ __align__(16) u16 A1[128 * 16];
    __shared__ __align__(16) u16 Hs[128 * 136];   // hidden; reused as C
    int t = threadIdx.x;
    int e0 = blockIdx.x * 128;
    for (int i = t; i < 128 * 16; i += 256) {
        int r = i >> 4, k = i & 15;
        int eg = min(e0 + r, E_ - 1);
        A1[i] = (k < 10) ? (u16)f2bf(ea[(size_t)eg * 10 + k]) : (u16)0;
    }
    __syncthreads();

    const int w = t >> 6, lane = t & 63;
    const int wm = w >> 1, wn = w & 1;
    const int l31 = lane & 31, lhi = lane >> 5;

    const u16* pb1[2];
    const u16* pb2[2];
    #pragma unroll
    for (int nf = 0; nf < 2; ++nf) {
        int n = wn * 64 + nf * 32 + l31;
        pb1[nf] = W1t + (size_t)n * 16;
        pb2[nf] = W2t + (size_t)n * 128;
    }

    f32x16 acc[2][2];
    #pragma unroll
    for (int nf = 0; nf < 2; ++nf) {
        float bv = b1[wn * 64 + nf * 32 + l31];
        #pragma unroll
        for (int mf = 0; mf < 2; ++mf)
            #pragma unroll
            for (int q = 0; q < 16; ++q) acc[mf][nf][q] = bv;
    }
    // GEMM1: K=16 (single step); A from LDS, B direct from global
    {
        bf16x8 av[2], bv[2];
        #pragma unroll
        for (int mf = 0; mf < 2; ++mf)
            av[mf] = *reinterpret_cast<const bf16x8*>(
                &A1[(wm * 64 + mf * 32 + l31) * 16 + lhi * 8]);
        #pragma unroll
        for (int nf = 0; nf < 2; ++nf)
            bv[nf] = *reinterpret_cast<const bf16x8*>(pb1[nf] + lhi * 8);
        #pragma unroll
        for (int mf = 0; mf < 2; ++mf)
            #pragma unroll
            for (int nf = 0; nf < 2; ++nf)
                acc[mf][nf] = __builtin_amdgcn_mfma_f32_32x32x16_bf16(
                    av[mf], bv[nf], acc[mf][nf], 0, 0, 0);
    }
    // ReLU -> Hs
    #pragma unroll
    for (int mf = 0; mf < 2; ++mf)
        #pragma unroll
        for (int nf = 0; nf < 2; ++nf) {
            int colbase = wn * 64 + nf * 32 + l31;
            int rowbase = wm * 64 + mf * 32 + 4 * lhi;
            #pragma unroll
            for (int q = 0; q < 16; ++q) {
                int row = rowbase + (q & 3) + 8 * (q >> 2);
                Hs[row * 136 + colbase] = (u16)f2bf(fmaxf(acc[mf][nf][q], 0.f));
            }
        }
    #pragma unroll
    for (int nf = 0; nf < 2; ++nf) {
        float bv = b2[wn * 64 + nf * 32 + l31];
        #pragma unroll
        for (int mf = 0; mf < 2; ++mf)
            #pragma unroll
            for (int q = 0; q < 16; ++q) acc[mf][nf][q] = bv;
    }
    __syncthreads();
    // GEMM2: K=128, A from Hs, B direct from global
    #pragma unroll
    for (int kc = 0; kc < 8; ++kc) {
        int ko = kc * 16 + lhi * 8;
        bf16x8 av[2], bv[2];
        #pragma unroll
        for (int mf = 0; mf < 2; ++mf)
            av[mf] = *reinterpret_cast<const bf16x8*>(
                &Hs[(wm * 64 + mf * 32 + l31) * 136 + ko]);
        #pragma unroll
        for (int nf = 0; nf < 2; ++nf)
            bv[nf] = *reinterpret_cast<const bf16x8*>(pb2[nf] + ko);
        #pragma unroll
        for (int mf = 0; mf < 2; ++mf)
            #pragma unroll
            for (int nf = 0; nf < 2; ++nf)
                acc[mf][nf] = __builtin_amdgcn_mfma_f32_32x32x16_bf16(
                    av[mf], bv[nf], acc[mf][nf], 0, 0, 0);
    }
    // C overlay -> coalesced store
    __syncthreads();
    u16* C = Hs;
    #pragma unroll
    for (int mf = 0; mf < 2; ++mf)
        #pragma unroll
        for (int nf = 0; nf < 2; ++nf) {
            int colbase = wn * 64 + nf * 32 + l31;
            int rowbase = wm * 64 + mf * 32 + 4 * lhi;
            #pragma unroll
            for (int q = 0; q < 16; ++q) {
                int row = rowbase + (q & 3) + 8 * (q >> 2);
                C[row * 136 + colbase] = (u16)f2bf(acc[mf][nf][q]);
            }
        }
    __syncthreads();
    for (int i = t; i < 128 * 32; i += 256) {
        int r = i >> 5, c4 = (i & 31) * 4;
        if (e0 + r < E_)
            *(uint2*)&e_bf[(size_t)(e0 + r) * 128 + c4] = *(uint2*)&C[r * 136 + c4];
    }
}

// -------- edge message + segmented scatter (direct-load MFMA, tier 3) ------
__global__ __launch_bounds__(256, 4) void edge_mp_sorted_kernel(
    const u16* __restrict__ h_bf, const u16* __restrict__ e_bf,
    const int* __restrict__ src_s, const int* __restrict__ dst_s,
    const int* __restrict__ permE,
    const u16* __restrict__ W1t, const float* __restrict__ b1,
    const u16* __restrict__ W2t, const float* __restrict__ b2,
    float* __restrict__ agg, int E_) {
    __shared__ __align__(16) u16 Hs[128 * 136];   // hidden; reused as C
    __shared__ int dst_sh[128];
    int t = threadIdx.x;
    int e0 = blockIdx.x * 128;
    if (t < 128) dst_sh[t] = dst_s[min(e0 + t, E_ - 1)];

    const int w = t >> 6, lane = t & 63;
    const int wm = w >> 1, wn = w & 1;
    const int l31 = lane & 31, lhi = lane >> 5;

    // per-lane A-row base pointers (3 K-regions x 2 m-fragments)
    const u16* pa0[2]; const u16* pa1[2]; const u16* pa2[2];
    #pragma unroll
    for (int mf = 0; mf < 2; ++mf) {
        int ge = min(e0 + wm * 64 + mf * 32 + l31, E_ - 1);
        pa0[mf] = h_bf + (size_t)src_s[ge] * 128;
        pa1[mf] = h_bf + (size_t)dst_s[ge] * 128;
        pa2[mf] = e_bf + (size_t)permE[ge] * 128;
    }
    const u16* pb1[2];
    const u16* pb2[2];
    #pragma unroll
    for (int nf = 0; nf < 2; ++nf) {
        int n = wn * 64 + nf * 32 + l31;
        pb1[nf] = W1t + (size_t)n * 384;
        pb2[nf] = W2t + (size_t)n * 128;
    }

    f32x16 acc[2][2];
    #pragma unroll
    for (int nf = 0; nf < 2; ++nf) {
        float bv = b1[wn * 64 + nf * 32 + l31];
        #pragma unroll
        for (int mf = 0; mf < 2; ++mf)
            #pragma unroll
            for (int q = 0; q < 16; ++q) acc[mf][nf][q] = bv;
    }

    // -------- GEMM1: K=384, A and B direct global->register, 0 barriers ----
    #pragma unroll
    for (int kc = 0; kc < 24; ++kc) {            // 24 chunks of K=16
        int ko = (kc & 7) * 16 + lhi * 8;        // offset within region
        bf16x8 av[2], bv[2];
        #pragma unroll
        for (int mf = 0; mf < 2; ++mf) {
            if (kc < 8)       av[mf] = *reinterpret_cast<const bf16x8*>(pa0[mf] + ko);
            else if (kc < 16) av[mf] = *reinterpret_cast<const bf16x8*>(pa1[mf] + ko);
            else              av[mf] = *reinterpret_cast<const bf16x8*>(pa2[mf] + ko);
        }
        #pragma unroll
        for (int nf = 0; nf < 2; ++nf)
            bv[nf] = *reinterpret_cast<const bf16x8*>(pb1[nf] + kc * 16 + lhi * 8);
        #pragma unroll
        for (int mf = 0; mf < 2; ++mf)
            #pragma unroll
            for (int nf = 0; nf < 2; ++nf)
                acc[mf][nf] = __builtin_amdgcn_mfma_f32_32x32x16_bf16(
                    av[mf], bv[nf], acc[mf][nf], 0, 0, 0);
    }

    // -------- ReLU + bf16 -> Hs --------
    #pragma unroll
    for (int mf = 0; mf < 2; ++mf)
        #pragma unroll
        for (int nf = 0; nf < 2; ++nf) {
            int colbase = wn * 64 + nf * 32 + l31;
            int rowbase = wm * 64 + mf * 32 + 4 * lhi;
            #pragma unroll
            for (int q = 0; q < 16; ++q) {
                int row = rowbase + (q & 3) + 8 * (q >> 2);
                Hs[row * 136 + colbase] = (u16)f2bf(fmaxf(acc[mf][nf][q], 0.f));
            }
        }
    #pragma unroll
    for (int nf = 0; nf < 2; ++nf) {
        float bv = b2[wn * 64 + nf * 32 + l31];
        #pragma unroll
        for (int mf = 0; mf < 2; ++mf)
            #pragma unroll
            for (int q = 0; q < 16; ++q) acc[mf][nf][q] = bv;
    }
    __syncthreads();   // Hs visible (also covers dst_sh)

    // -------- GEMM2: K=128, A from Hs, B direct global ---------------------
    #pragma unroll
    for (int kc = 0; kc < 8; ++kc) {
        int ko = kc * 16 + lhi * 8;
        bf16x8 av[2], bv[2];
        #pragma unroll
        for (int mf = 0; mf < 2; ++mf)
            av[mf] = *reinterpret_cast<const bf16x8*>(
                &Hs[(wm * 64 + mf * 32 + l31) * 136 + ko]);
        #pragma unroll
        for (int nf = 0; nf < 2; ++nf)
            bv[nf] = *reinterpret_cast<const bf16x8*>(pb2[nf] + ko);
        #pragma unroll
        for (int mf = 0; mf < 2; ++mf)
            #pragma unroll
            for (int nf = 0; nf < 2; ++nf)
                acc[mf][nf] = __builtin_amdgcn_mfma_f32_32x32x16_bf16(
                    av[mf], bv[nf], acc[mf][nf], 0, 0, 0);
    }

    // -------- C -> LDS (overlay Hs), segmented reduce, few atomics ---------
    __syncthreads();   // all Hs reads done
    u16* C = Hs;       // stride 136
    #pragma unroll
    for (int mf = 0; mf < 2; ++mf)
        #pragma unroll
        for (int nf = 0; nf < 2; ++nf) {
            int colbase = wn * 64 + nf * 32 + l31;
            int rowbase = wm * 64 + mf * 32 + 4 * lhi;
            #pragma unroll
            for (int q = 0; q < 16; ++q) {
                int row = rowbase + (q & 3) + 8 * (q >> 2);
                C[row * 136 + colbase] = (u16)f2bf(acc[mf][nf][q]);
            }
        }
    __syncthreads();
    {
        int col = t & 127, seg = t >> 7;
        int r0 = seg * 64, r1 = r0 + 64;
        float s = 0.f; int cur = -1;
        for (int r = r0; r < r1; ++r) {
            if (e0 + r >= E_) break;
            int d = dst_sh[r];
            float v = bf2f(C[r * 136 + col]);
            if (d != cur) {
                if (cur >= 0) unsafeAtomicAdd(&agg[(size_t)cur * 128 + col], s);
                cur = d; s = v;
            } else s += v;
        }
        if (cur >= 0) unsafeAtomicAdd(&agg[(size_t)cur * 128 + col], s);
    }
}

// --------- node update (direct-load MFMA + residual, tier 3) ----------------
__global__ __launch_bounds__(256, 4) void node_mp_mfma_kernel(
    float* __restrict__ h, u16* __restrict__ h_bf,
    const float* __restrict__ agg,
    const u16* __restrict__ W1t, const float* __restrict__ b1,
    const u16* __restrict__ W2t, const float* __restrict__ b2, int N_) {
    __shared__ __align__(16) u16 Hs[128 * 136];   // hidden; reused as C
    int t = threadIdx.x;
    int n0 = blockIdx.x * 128;

    const int w = t >> 6, lane = t & 63;
    const int wm = w >> 1, wn = w & 1;
    const int l31 = lane & 31, lhi = lane >> 5;

    const u16* pah[2]; const float* pag[2];
    #pragma unroll
    for (int mf = 0; mf < 2; ++mf) {
        int n = min(n0 + wm * 64 + mf * 32 + l31, N_ - 1);
        pah[mf] = h_bf + (size_t)n * 128;
        pag[mf] = agg + (size_t)n * 128;
    }
    const u16* pb1[2];
    const u16* pb2[2];
    #pragma unroll
    for (int nf = 0; nf < 2; ++nf) {
        int n = wn * 64 + nf * 32 + l31;
        pb1[nf] = W1t + (size_t)n * 256;
        pb2[nf] = W2t + (size_t)n * 128;
    }

    f32x16 acc[2][2];
    #pragma unroll
    for (int nf = 0; nf < 2; ++nf) {
        float bv = b1[wn * 64 + nf * 32 + l31];
        #pragma unroll
        for (int mf = 0; mf < 2; ++mf)
            #pragma unroll
            for (int q = 0; q < 16; ++q) acc[mf][nf][q] = bv;
    }

    // -------- GEMM1: K=256 (h_bf | f32 agg converted in-flight) ------------
    #pragma unroll
    for (int kc = 0; kc < 16; ++kc) {
        int ko = (kc & 7) * 16 + lhi * 8;
        bf16x8 av[2], bv[2];
        #pragma unroll
        for (int mf = 0; mf < 2; ++mf) {
            if (kc < 8) {
                av[mf] = *reinterpret_cast<const bf16x8*>(pah[mf] + ko);
            } else {
                const float* ap = pag[mf] + ko;
                float4 a0 = *(const float4*)ap;
                float4 a1 = *(const float4*)(ap + 4);
                ushort8 v;
                v[0] = (u16)f2bf(a0.x); v[1] = (u16)f2bf(a0.y);
                v[2] = (u16)f2bf(a0.z); v[3] = (u16)f2bf(a0.w);
                v[4] = (u16)f2bf(a1.x); v[5] = (u16)f2bf(a1.y);
                v[6] = (u16)f2bf(a1.z); v[7] = (u16)f2bf(a1.w);
                av[mf] = *reinterpret_cast<const bf16x8*>(&v);
            }
        }
        #pragma unroll
        for (int nf = 0; nf < 2; ++nf)
            bv[nf] = *reinterpret_cast<const bf16x8*>(pb1[nf] + kc * 16 + lhi * 8);
        #pragma unroll
        for (int mf = 0; mf < 2; ++mf)
            #pragma unroll
            for (int nf = 0; nf < 2; ++nf)
                acc[mf][nf] = __builtin_amdgcn_mfma_f32_32x32x16_bf16(
                    av[mf], bv[nf], acc[mf][nf], 0, 0, 0);
    }

    // -------- ReLU -> Hs --------
    #pragma unroll
    for (int mf = 0; mf < 2; ++mf)
        #pragma unroll
        for (int nf = 0; nf < 2; ++nf) {
            int colbase = wn * 64 + nf * 32 + l31;
            int rowbase = wm * 64 + mf * 32 + 4 * lhi;
            #pragma unroll
            for (int q = 0; q < 16; ++q) {
                int row = rowbase + (q & 3) + 8 * (q >> 2);
                Hs[row * 136 + colbase] = (u16)f2bf(fmaxf(acc[mf][nf][q], 0.f));
            }
        }
    #pragma unroll
    for (int nf = 0; nf < 2; ++nf) {
        float bv = b2[wn * 64 + nf * 32 + l31];
        #pragma unroll
        for (int mf = 0; mf < 2; ++mf)
            #pragma unroll
            for (int q = 0; q < 16; ++q) acc[mf][nf][q] = bv;
    }
    __syncthreads();

    // -------- GEMM2: K=128 --------
    #pragma unroll
    for (int kc = 0; kc < 8; ++kc) {
        int ko = kc * 16 + lhi * 8;
        bf16x8 av[2], bv[2];
        #pragma unroll
        for (int mf = 0; mf < 2; ++mf)
            av[mf] = *reinterpret_cast<const bf16x8*>(
                &Hs[(wm * 64 + mf * 32 + l31) * 136 + ko]);
        #pragma unroll
        for (int nf = 0; nf < 2; ++nf)
            bv[nf] = *reinterpret_cast<const bf16x8*>(pb2[nf] + ko);
        #pragma unroll
        for (int mf = 0; mf < 2; ++mf)
            #pragma unroll
            for (int nf = 0; nf < 2; ++nf)
                acc[mf][nf] = __builtin_amdgcn_mfma_f32_32x32x16_bf16(
                    av[mf], bv[nf], acc[mf][nf], 0, 0, 0);
    }

    // -------- C -> LDS, residual epilogue (coalesced) --------
    __syncthreads();
    u16* C = Hs;
    #pragma unroll
    for (int mf = 0; mf < 2; ++mf)
        #pragma unroll
        for (int nf = 0; nf < 2; ++nf) {
            int colbase = wn * 64 + nf * 32 + l31;
            int rowbase = wm * 64 + mf * 32 + 4 * lhi;
            #pragma unroll
            for (int q = 0; q < 16; ++q) {
                int row = rowbase + (q & 3) + 8 * (q >> 2);
                C[row * 136 + colbase] = (u16)f2bf(acc[mf][nf][q]);
            }
        }
    __syncthreads();
    for (int i = t; i < 128 * 32; i += 256) {
        int r = i >> 5, c4 = (i & 31) * 4;
        int n = n0 + r;
        if (n < N_) {
            float4 hv = *(const float4*)&h[(size_t)n * 128 + c4];
            hv.x += bf2f(C[r * 136 + c4 + 0]);
            hv.y += bf2f(C[r * 136 + c4 + 1]);
            hv.z += bf2f(C[r * 136 + c4 + 2]);
            hv.w += bf2f(C[r * 136 + c4 + 3]);
            *(float4*)&h[(size_t)n * 128 + c4] = hv;
            unsigned p0 = f2bf(hv.x) | (f2bf(hv.y) << 16);
            unsigned p1 = f2bf(hv.z) | (f2bf(hv.w) << 16);
            *(uint2*)&h_bf[(size_t)n * 128 + c4] = make_uint2(p0, p1);
        }
    }
}

// ------------- edge message + scatter: bf16 MFMA (tier 2 fallback) ---------
__global__ __launch_bounds__(256) void edge_mp_mfma_kernel(
    const u16* __restrict__ h_bf, const u16* __restrict__ e_bf,
    const int* __restrict__ src, const int* __restrict__ dst,
    const u16* __restrict__ W1t, const float* __restrict__ b1,
    const u16* __restrict__ W2t, const float* __restrict__ b2,
    float* __restrict__ agg, int E_) {
    __shared__ __align__(16) u16 A1[128 * 40];
    __shared__ __align__(16) u16 Bl[128 * 40];
    __shared__ __align__(16) u16 A2[128 * 136];
    __shared__ int idx_s[256];
    int t = threadIdx.x;
    int e0 = blockIdx.x * 128;
    if (t < 128) idx_s[t] = src[min(e0 + t, E_ - 1)];
    else         idx_s[t] = dst[min(e0 + t - 128, E_ - 1)];
    __syncthreads();

    const int w = t >> 6, lane = t & 63;
    const int wm = w >> 1, wn = w & 1;
    const int l31 = lane & 31, lhi = lane >> 5;

    f32x16 acc[2][2];
    #pragma unroll
    for (int nf = 0; nf < 2; ++nf) {
        float bv = b1[wn * 64 + nf * 32 + l31];
        #pragma unroll
        for (int mf = 0; mf < 2; ++mf)
            #pragma unroll
            for (int q = 0; q < 16; ++q) acc[mf][nf][q] = bv;
    }
    for (int s = 0; s < 12; ++s) {
        int ks = s * 32;
        #pragma unroll
        for (int cc = 0; cc < 2; ++cc) {
            int c = t + cc * 256;
            int r = c >> 2, ch = c & 3;
            int kcol = (ks & 127) + ch * 8;
            const u16* sp;
            if (ks < 128)      sp = h_bf + (size_t)idx_s[r] * 128 + kcol;
            else if (ks < 256) sp = h_bf + (size_t)idx_s[128 + r] * 128 + kcol;
            else               sp = e_bf + (size_t)min(e0 + r, E_ - 1) * 128 + kcol;
            *(ushort8*)&A1[r * 40 + ch * 8] = *(const ushort8*)sp;
        }
        #pragma unroll
        for (int cc = 0; cc < 2; ++cc) {
            int c = t + cc * 256;
            int n = c >> 2, ch = c & 3;
            *(ushort8*)&Bl[n * 40 + ch * 8] =
                *(const ushort8*)&W1t[(size_t)n * 384 + ks + ch * 8];
        }
        __syncthreads();
        #pragma unroll
        for (int kh = 0; kh < 2; ++kh) {
            int koff = kh * 16 + lhi * 8;
            bf16x8 av[2], bv[2];
            #pragma unroll
            for (int mf = 0; mf < 2; ++mf)
                av[mf] = *reinterpret_cast<const bf16x8*>(
                    &A1[(wm * 64 + mf * 32 + l31) * 40 + koff]);
            #pragma unroll
            for (int nf = 0; nf < 2; ++nf)
                bv[nf] = *reinterpret_cast<const bf16x8*>(
                    &Bl[(wn * 64 + nf * 32 + l31) * 40 + koff]);
            #pragma unroll
            for (int mf = 0; mf < 2; ++mf)
                #pragma unroll
                for (int nf = 0; nf < 2; ++nf)
                    acc[mf][nf] = __builtin_amdgcn_mfma_f32_32x32x16_bf16(
                        av[mf], bv[nf], acc[mf][nf], 0, 0, 0);
        }
        __syncthreads();
    }
    #pragma unroll
    for (int mf = 0; mf < 2; ++mf)
        #pragma unroll
        for (int nf = 0; nf < 2; ++nf) {
            int colbase = wn * 64 + nf * 32 + l31;
            int rowbase = wm * 64 + mf * 32 + 4 * lhi;
            #pragma unroll
            for (int q = 0; q < 16; ++q) {
                int row = rowbase + (q & 3) + 8 * (q >> 2);
                A2[row * 136 + colbase] = (u16)f2bf(fmaxf(acc[mf][nf][q], 0.f));
            }
        }
    #pragma unroll
    for (int nf = 0; nf < 2; ++nf) {
        float bv = b2[wn * 64 + nf * 32 + l31];
        #pragma unroll
        for (int mf = 0; mf < 2; ++mf)
            #pragma unroll
            for (int q = 0; q < 16; ++q) acc[mf][nf][q] = bv;
    }
    for (int s = 0; s < 4; ++s) {
        int ks = s * 32;
        __syncthreads();
        #pragma unroll
        for (int cc = 0; cc < 2; ++cc) {
            int c = t + cc * 256;
            int n = c >> 2, ch = c & 3;
            *(ushort8*)&Bl[n * 40 + ch * 8] =
                *(const ushort8*)&W2t[(size_t)n * 128 + ks + ch * 8];
        }
        __syncthreads();
        #pragma unroll
        for (int kh = 0; kh < 2; ++kh) {
            int koff = kh * 16 + lhi * 8;
            bf16x8 av[2], bv[2];
            #pragma unroll
            for (int mf = 0; mf < 2; ++mf)
                av[mf] = *reinterpret_cast<const bf16x8*>(
                    &A2[(wm * 64 + mf * 32 + l31) * 136 + ks + koff]);
            #pragma unroll
            for (int nf = 0; nf < 2; ++nf)
                bv[nf] = *reinterpret_cast<const bf16x8*>(
                    &Bl[(wn * 64 + nf * 32 + l31) * 40 + koff]);
            #pragma unroll
            for (int mf = 0; mf < 2; ++mf)
                #pragma unroll
                for (int nf = 0; nf < 2; ++nf)
                    acc[mf][nf] = __builtin_amdgcn_mfma_f32_32x32x16_bf16(
                        av[mf], bv[nf], acc[mf][nf], 0, 0, 0);
        }
    }
    #pragma unroll
    for (int mf = 0; mf < 2; ++mf)
        #pragma unroll
        for (int nf = 0; nf < 2; ++nf) {
            int colbase = wn * 64 + nf * 32 + l31;
            int rowbase = wm * 64 + mf * 32 + 4 * lhi;
            #pragma unroll
            for (int q = 0; q < 16; ++q) {
                int row = rowbase + (q & 3) + 8 * (q >> 2);
                if (e0 + row < E_)
                    unsafeAtomicAdd(&agg[(size_t)idx_s[128 + row] * 128 + colbase],
                                    acc[mf][nf][q]);
            }
        }
}

// ------------- edge message + scatter (tier 1: f32 VALU) -------------------
__global__ __launch_bounds__(256) void edge_mp_a_kernel(
    const float* __restrict__ h, const u16* __restrict__ e,
    const int* __restrict__ src, const int* __restrict__ dst,
    const float* __restrict__ W1, const float* __restrict__ b1,
    const float* __restrict__ W2, const float* __restrict__ b2,
    float* __restrict__ agg, int E_) {
    __shared__ float buf[TILE * 384];
    __shared__ int idx_s[2 * TILE];
    int t = threadIdx.x;
    int e0 = blockIdx.x * TILE;
    if (t < TILE) idx_s[t] = src[min(e0 + t, E_ - 1)];
    else if (t < 2 * TILE) idx_s[t] = dst[min(e0 + t - TILE, E_ - 1)];
    __syncthreads();
    for (int i = t; i < TILE * 96; i += 256) {
        int r = i / 96, col = (i % 96) * 4;
        float4 v;
        if (col < 128)      v = *(const float4*)&h[(size_t)idx_s[r] * 128 + col];
        else if (col < 256) v = *(const float4*)&h[(size_t)idx_s[TILE + r] * 128 + (col - 128)];
        else {
            uint2 u = *(const uint2*)&e[(size_t)min(e0 + r, E_ - 1) * 128 + (col - 256)];
            v = make_float4(bf2f(u.x & 0xffffu), bf2f(u.x >> 16),
                            bf2f(u.y & 0xffffu), bf2f(u.y >> 16));
        }
        *(float4*)&buf[r * 384 + col] = v;
    }
    __syncthreads();
    int jq = (t & 31) * 4, rg = t >> 5;
    float acc[4][4];
    gemm_tile_phase<384, 384, 128>(buf, W1, b1, acc, jq, rg);
    __syncthreads();
    #pragma unroll
    for (int rr = 0; rr < 4; ++rr)
        *(float4*)&buf[(rg + rr * 8) * 128 + jq] = relu4(acc[rr]);
    __syncthreads();
    gemm_tile_phase<128, 128, 128>(buf, W2, b2, acc, jq, rg);
    #pragma unroll
    for (int rr = 0; rr < 4; ++rr) {
        int row = rg + rr * 8;
        int eg = e0 + row;
        if (eg < E_) {
            float* dstp = &agg[(size_t)idx_s[TILE + row] * 128 + jq];
            unsafeAtomicAdd(dstp + 0, acc[rr][0]);
            unsafeAtomicAdd(dstp + 1, acc[rr][1]);
            unsafeAtomicAdd(dstp + 2, acc[rr][2]);
            unsafeAtomicAdd(dstp + 3, acc[rr][3]);
        }
    }
}

// ---------- edge message + scatter (tier 0: recompute encoder) -------------
__global__ __launch_bounds__(256) void edge_mp_b_kernel(
    const float* __restrict__ h, const float* __restrict__ ea,
    const int* __restrict__ src, const int* __restrict__ dst,
    const float* __restrict__ eW1, const float* __restrict__ eb1,
    const float* __restrict__ eW2, const float* __restrict__ eb2,
    const float* __restrict__ W1, const float* __restrict__ b1,
    const float* __restrict__ W2, const float* __restrict__ b2,
    float* __restrict__ agg, int E_) {
    __shared__ float buf[TILE * 384];
    __shared__ float in10[TILE * 12];
    __shared__ int idx_s[2 * TILE];
    int t = threadIdx.x;
    int e0 = blockIdx.x * TILE;
    if (t < TILE) idx_s[t] = src[min(e0 + t, E_ - 1)];
    else if (t < 2 * TILE) idx_s[t] = dst[min(e0 + t - TILE, E_ - 1)];
    for (int i = t; i < TILE * 12; i += 256) {
        int r = i / 12, k = i % 12;
        int eg = min(e0 + r, E_ - 1);
        in10[i] = (k < 10) ? ea[(size_t)eg * 10 + k] : 0.f;
    }
    __syncthreads();
    int jq = (t & 31) * 4, rg = t >> 5;
    float acc[4][4];
    gemm_tile_phase<10, 12, 128>(in10, eW1, eb1, acc, jq, rg);
    #pragma unroll
    for (int rr = 0; rr < 4; ++rr)
        *(float4*)&buf[(rg + rr * 8) * 384 + 128 + jq] = relu4(acc[rr]);
    __syncthreads();
    gemm_tile_phase<128, 384, 128>(buf + 128, eW2, eb2, acc, jq, rg);
    __syncthreads();
    #pragma unroll
    for (int rr = 0; rr < 4; ++rr)
        *(float4*)&buf[(rg + rr * 8) * 384 + 256 + jq] =
            make_float4(acc[rr][0], acc[rr][1], acc[rr][2], acc[rr][3]);
    __syncthreads();
    for (int i = t; i < TILE * 64; i += 256) {
        int r = i / 64, col = (i % 64) * 4;
        float4 v = (col < 128)
            ? *(const float4*)&h[(size_t)idx_s[r] * 128 + col]
            : *(const float4*)&h[(size_t)idx_s[TILE + r] * 128 + (col - 128)];
        *(float4*)&buf[r * 384 + col] = v;
    }
    __syncthreads();
    gemm_tile_phase<384, 384, 128>(buf, W1, b1, acc, jq, rg);
    __syncthreads();
    #pragma unroll
    for (int rr = 0; rr < 4; ++rr)
        *(float4*)&buf[(rg + rr * 8) * 128 + jq] = relu4(acc[rr]);
    __syncthreads();
    gemm_tile_phase<128, 128, 128>(buf, W2, b2, acc, jq, rg);
    #pragma unroll
    for (int rr = 0; rr < 4; ++rr) {
        int row = rg + rr * 8;
        int eg = e0 + row;
        if (eg < E_) {
            float* dstp = &agg[(size_t)idx_s[TILE + row] * 128 + jq];
            unsafeAtomicAdd(dstp + 0, acc[rr][0]);
            unsafeAtomicAdd(dstp + 1, acc[rr][1]);
            unsafeAtomicAdd(dstp + 2, acc[rr][2]);
            unsafeAtomicAdd(dstp + 3, acc[rr][3]);
        }
    }
}

// --------------------- node update (f32 VALU, tiers 0-2) -------------------
__global__ __launch_bounds__(256) void node_mp_kernel(
    float* __restrict__ h, u16* __restrict__ h_bf,
    const float* __restrict__ agg,
    const float* __restrict__ W1, const float* __restrict__ b1,
    const float* __restrict__ W2, const float* __restrict__ b2, int N_) {
    __shared__ float buf[TILE * 256];
    int t = threadIdx.x;
    int n0 = blockIdx.x * TILE;
    for (int i = t; i < TILE * 64; i += 256) {
        int r = i / 64, col = (i % 64) * 4;
        int n = min(n0 + r, N_ - 1);
        float4 v = (col < 128) ? *(const float4*)&h[(size_t)n * 128 + col]
                               : *(const float4*)&agg[(size_t)n * 128 + (col - 128)];
        *(float4*)&buf[r * 256 + col] = v;
    }
    __syncthreads();
    int jq = (t & 31) * 4, rg = t >> 5;
    float acc[4][4];
    gemm_tile_phase<256, 256, 128>(buf, W1, b1, acc, jq, rg);
    __syncthreads();
    #pragma unroll
    for (int rr = 0; rr < 4; ++rr)
        *(float4*)&buf[(rg + rr * 8) * 128 + jq] = relu4(acc[rr]);
    __syncthreads();
    gemm_tile_phase<128, 128, 128>(buf, W2, b2, acc, jq, rg);
    #pragma unroll
    for (int rr = 0; rr < 4; ++rr) {
        int n = n0 + rg + rr * 8;
        if (n < N_) {
            float4 old = *(const float4*)&h[(size_t)n * 128 + jq];
            old.x += acc[rr][0]; old.y += acc[rr][1];
            old.z += acc[rr][2]; old.w += acc[rr][3];
            *(float4*)&h[(size_t)n * 128 + jq] = old;
            if (h_bf) {
                unsigned p0 = f2bf(old.x) | (f2bf(old.y) << 16);
                unsigned p1 = f2bf(old.z) | (f2bf(old.w) << 16);
                *(uint2*)&h_bf[(size_t)n * 128 + jq] = make_uint2(p0, p1);
            }
        }
    }
}

// -------------------------------- decoder ---------------------------------
__global__ __launch_bounds__(256) void decoder_kernel(
    const float* __restrict__ h,
    const float* __restrict__ W1, const float* __restrict__ b1,
    const float* __restrict__ W2, const float* __restrict__ b2,
    const float* __restrict__ W3, const float* __restrict__ b3,
    const float* __restrict__ bc_disp, const float* __restrict__ bc_rot,
    float* __restrict__ out, int N_) {
    __shared__ float in_lds[TILE * 128];
    __shared__ float hid2[TILE * 64];
    int t = threadIdx.x;
    int n0 = blockIdx.x * TILE;
    for (int i = t; i < TILE * 32; i += 256) {
        int r = i / 32, col = (i % 32) * 4;
        int n = min(n0 + r, N_ - 1);
        *(float4*)&in_lds[r * 128 + col] = *(const float4*)&h[(size_t)n * 128 + col];
    }
    __syncthreads();
    int jq = (t & 31) * 4, rg = t >> 5;
    float acc[4][4];
    gemm_tile_phase<128, 128, 128>(in_lds, W1, b1, acc, jq, rg);
    __syncthreads();
    #pragma unroll
    for (int rr = 0; rr < 4; ++rr)
        *(float4*)&in_lds[(rg + rr * 8) * 128 + jq] = relu4(acc[rr]);
    __syncthreads();
    if ((t & 31) < 16) {
        float acc2[4][4];
        int jq2 = (t & 31) * 4;
        gemm_tile_phase<128, 128, 64>(in_lds, W2, b2, acc2, jq2, rg);
        #pragma unroll
        for (int rr = 0; rr < 4; ++rr)
            *(float4*)&hid2[(rg + rr * 8) * 64 + jq2] = relu4(acc2[rr]);
    }
    __syncthreads();
    if (t < TILE * 3) {
        int r = t / 3, c = t % 3;
        int n = n0 + r;
        if (n < N_) {
            float a = b3[c];
            for (int k = 0; k < 64; ++k) a += hid2[r * 64 + k] * W3[k * 3 + c];
            float m = (c == 2) ? (1.f - bc_rot[n]) : (1.f - bc_disp[n]);
            out[(size_t)n * 3 + c] = a * m;
        }
    }
}

// ------------------------------- launcher ----------------------------------
extern "C" void kernel_launch(void* const* d_in, const int* in_sizes, int n_in,
                              void* d_out, int out_size, void* d_ws, size_t ws_size,
                              hipStream_t stream) {
    const float* x        = (const float*)d_in[0];
    const float* coords   = (const float*)d_in[1];
    const float* ea       = (const float*)d_in[2];
    const int*   eidx     = (const int*)d_in[3];
    const float* bc_disp  = (const float*)d_in[4];
    const float* bc_rot   = (const float*)d_in[5];
    const float* enc_nW1  = (const float*)d_in[6];
    const float* enc_nb1  = (const float*)d_in[7];
    const float* enc_nW2  = (const float*)d_in[8];
    const float* enc_nb2  = (const float*)d_in[9];
    const float* enc_eW1  = (const float*)d_in[10];
    const float* enc_eb1  = (const float*)d_in[11];
    const float* enc_eW2  = (const float*)d_in[12];
    const float* enc_eb2  = (const float*)d_in[13];
    const float* mp_eW1   = (const float*)d_in[14];
    const float* mp_eb1   = (const float*)d_in[15];
    const float* mp_eW2   = (const float*)d_in[16];
    const float* mp_eb2   = (const float*)d_in[17];
    const float* mp_nW1   = (const float*)d_in[18];
    const float* mp_nb1   = (const float*)d_in[19];
    const float* mp_nW2   = (const float*)d_in[20];
    const float* mp_nb2   = (const float*)d_in[21];
    const float* dec_W1   = (const float*)d_in[22];
    const float* dec_b1   = (const float*)d_in[23];
    const float* dec_W2   = (const float*)d_in[24];
    const float* dec_b2   = (const float*)d_in[25];
    const float* dec_W3   = (const float*)d_in[26];
    const float* dec_b3   = (const float*)d_in[27];

    const int N = in_sizes[0] / 9;
    const int E = in_sizes[2] / 10;
    const int L = in_sizes[15] / 128;   // mp_eb1 is (L,128)
    const int H = 128;

    const int* src = eidx;
    const int* dst = eidx + E;

    const size_t nh = (size_t)N * H;
    const size_t eh = (size_t)E * H;

    const int nblk    = (N + TILE - 1) / TILE;
    const int eblk    = (E + TILE - 1) / TILE;
    const int nblk128 = (N + 127) / 128;
    const int eblk128 = (E + 127) / 128;

    // ---------------- tier 3 workspace layout ----------------
    char* p = (char*)d_ws;
    float* h      = (float*)p;                 p += nh * 4;
    float* agg    = (float*)p;                 p += nh * 4;
    u16*   h_bf   = (u16*)p;                   p += nh * 2;
    u16*   e_bf3  = (u16*)p;                   p += eh * 2;
    u16*   W1t_e  = (u16*)p;                   p += (size_t)L * 128 * 384 * 2;
    u16*   W2t_e  = (u16*)p;                   p += (size_t)L * 128 * 128 * 2;
    u16*   W1t_n  = (u16*)p;                   p += (size_t)L * 128 * 256 * 2;
    u16*   W2t_n  = (u16*)p;                   p += (size_t)L * 128 * 128 * 2;
    u16*   W1t_ee = (u16*)p;                   p += (size_t)128 * 16 * 2;
    u16*   W2t_ee = (u16*)p;                   p += (size_t)128 * 128 * 2;
    int*   cnt    = (int*)p;                   p += (size_t)N * 4;
    int*   row_ptr= (int*)p;                   p += (size_t)(N + 1) * 4;
    int*   fill   = (int*)p;                   p += (size_t)N * 4;
    int*   src_s  = (int*)p;                   p += (size_t)E * 4;
    int*   dst_s  = (int*)p;                   p += (size_t)E * 4;
    int*   permE  = (int*)p;                   p += (size_t)E * 4;
    const size_t need3 = (size_t)(p - (char*)d_ws);

    // tier-2 layout (round-3 compatible)
    u16* h_bf2 = (u16*)((float*)d_ws + 2 * nh);
    u16* e_bf2 = h_bf2 + nh;
    u16* W1t2  = e_bf2 + eh;
    u16* W2t2  = W1t2 + (size_t)L * 128 * 384;
    const size_t need2 = 2 * nh * 4 + nh * 2 + eh * 2 +
                         (size_t)L * (128 * 384 + 128 * 128) * 2;
    const size_t need1 = 2 * nh * 4 + eh * 2;

    const int tier = (ws_size >= need3) ? 3 :
                     (ws_size >= need2) ? 2 :
                     (ws_size >= need1) ? 1 : 0;

    if (tier == 3) {
        // weight prep
        wt_stacked_kernel<<<(int)(((size_t)L*128*384 + 255)/256), 256, 0, stream>>>(
            mp_eW1, W1t_e, L, 384, 384, 128);
        wt_stacked_kernel<<<(int)(((size_t)L*128*128 + 255)/256), 256, 0, stream>>>(
            mp_eW2, W2t_e, L, 128, 128, 128);
        wt_stacked_kernel<<<(int)(((size_t)L*128*256 + 255)/256), 256, 0, stream>>>(
            mp_nW1, W1t_n, L, 256, 256, 128);
        wt_stacked_kernel<<<(int)(((size_t)L*128*128 + 255)/256), 256, 0, stream>>>(
            mp_nW2, W2t_n, L, 128, 128, 128);
        wt_stacked_kernel<<<(128*16 + 255)/256, 256, 0, stream>>>(
            enc_eW1, W1t_ee, 1, 10, 16, 128);
        wt_stacked_kernel<<<(128*128 + 255)/256, 256, 0, stream>>>(
            enc_eW2, W2t_ee, 1, 128, 128, 128);
        // counting sort by dst
        hipMemsetAsync(cnt, 0, (size_t)N * 4, stream);
        hipMemsetAsync(fill, 0, (size_t)N * 4, stream);
        hist_kernel<<<(E + 255)/256, 256, 0, stream>>>(dst, cnt, E);
        scan_kernel<<<1, 1024, 0, stream>>>(cnt, row_ptr, N);
        scatter_kernel<<<(E + 255)/256, 256, 0, stream>>>(
            src, dst, row_ptr, fill, src_s, dst_s, permE, E);
        // encoders
        node_enc_kernel<<<nblk, 256, 0, stream>>>(x, coords, enc_nW1, enc_nb1,
                                                  enc_nW2, enc_nb2, h, h_bf, N);
        edge_enc_mfma_kernel<<<eblk128, 256, 0, stream>>>(
            ea, W1t_ee, enc_eb1, W2t_ee, enc_eb2, e_bf3, E);
        // layers
        for (int l = 0; l < L; ++l) {
            hipMemsetAsync(agg, 0, nh * 4, stream);
            edge_mp_sorted_kernel<<<eblk128, 256, 0, stream>>>(
                h_bf, e_bf3, src_s, dst_s, permE,
                W1t_e + (size_t)l * 128 * 384, mp_eb1 + (size_t)l * H,
                W2t_e + (size_t)l * 128 * 128, mp_eb2 + (size_t)l * H,
                agg, E);
            node_mp_mfma_kernel<<<nblk128, 256, 0, stream>>>(
                h, h_bf, agg,
                W1t_n + (size_t)l * 128 * 256, mp_nb1 + (size_t)l * H,
                W2t_n + (size_t)l * 128 * 128, mp_nb2 + (size_t)l * H,
                N);
        }
        decoder_kernel<<<nblk, 256, 0, stream>>>(h, dec_W1, dec_b1, dec_W2, dec_b2,
                                                 dec_W3, dec_b3, bc_disp, bc_rot,
                                                 (float*)d_out, N);
        return;
    }

    // ---------------- tiers 0-2 (previous fallbacks) ----------------
    node_enc_kernel<<<nblk, 256, 0, stream>>>(x, coords, enc_nW1, enc_nb1,
                                              enc_nW2, enc_nb2, h,
                                              tier == 2 ? h_bf2 : (u16*)nullptr, N);
    if (tier >= 1) {
        u16* e_t1 = (tier == 2) ? e_bf2 : (u16*)((float*)d_ws + 2 * nh);
        edge_enc_bf16_kernel<<<eblk, 256, 0, stream>>>(ea, enc_eW1, enc_eb1,
                                                       enc_eW2, enc_eb2, e_t1, E);
        if (tier == 2) {
            wt_stacked_kernel<<<(int)(((size_t)L*128*384 + 255)/256), 256, 0, stream>>>(
                mp_eW1, W1t2, L, 384, 384, 128);
            wt_stacked_kernel<<<(int)(((size_t)L*128*128 + 255)/256), 256, 0, stream>>>(
                mp_eW2, W2t2, L, 128, 128, 128);
        }
    }
    for (int l = 0; l < L; ++l) {
        hipMemsetAsync(agg, 0, nh * 4, stream);
        if (tier == 2) {
            edge_mp_mfma_kernel<<<eblk128, 256, 0, stream>>>(
                h_bf2, e_bf2, src, dst,
                W1t2 + (size_t)l * 128 * 384, mp_eb1 + (size_t)l * H,
                W2t2 + (size_t)l * 128 * 128, mp_eb2 + (size_t)l * H,
                agg, E);
        } else if (tier == 1) {
            edge_mp_a_kernel<<<eblk, 256, 0, stream>>>(
                h, (u16*)((float*)d_ws + 2 * nh), src, dst,
                mp_eW1 + (size_t)l * 3 * H * H, mp_eb1 + (size_t)l * H,
                mp_eW2 + (size_t)l * H * H,     mp_eb2 + (size_t)l * H,
                agg, E);
        } else {
            edge_mp_b_kernel<<<eblk, 256, 0, stream>>>(
                h, ea, src, dst,
                enc_eW1, enc_eb1, enc_eW2, enc_eb2,
                mp_eW1 + (size_t)l * 3 * H * H, mp_eb1 + (size_t)l * H,
                mp_eW2 + (size_t)l * H * H,     mp_eb2 + (size_t)l * H,
                agg, E);
        }
        node_mp_kernel<<<nblk, 256, 0, stream>>>(
            h, tier == 2 ? h_bf2 : (u16*)nullptr, agg,
            mp_nW1 + (size_t)l * 2 * H * H, mp_nb1 + (size_t)l * H,
            mp_nW2 + (size_t)l * H * H,     mp_nb2 + (size_t)l * H,
            N);
    }
    decoder_kernel<<<nblk, 256, 0, stream>>>(h, dec_W1, dec_b1, dec_W2, dec_b2,
                                             dec_W3, dec_b3, bc_disp, bc_rot,
                                             (float*)d_out, N);
}

// Round 10
// 1580.107 us; speedup vs baseline: 1.3174x; 1.3174x over previous
//
#include <hip/hip_runtime.h>

// ---------------------------------------------------------------------------
// PIGNN round 10:
//  - edge/node MLP: A staged in LDS (double-buffered, overlaid on hidden buf),
//    B (weights) read direct global->register (L1/L2-hot), 1 barrier/K-step,
//    36KB LDS -> 4 blocks/CU.
//  - edges counting-sorted by dst; segmented-reduce scatter (round 4).
//  Tier 3: full path. Tier 2/1/0: earlier fallbacks.
// ---------------------------------------------------------------------------

#define TILE 32   // rows per block for the f32 VALU kernels

typedef unsigned short u16;
typedef u16   ushort8 __attribute__((ext_vector_type(8)));
typedef __bf16 bf16x8 __attribute__((ext_vector_type(8)));
typedef float f32x16  __attribute__((ext_vector_type(16)));

__device__ __forceinline__ unsigned f2bf(float f) {      // RNE f32->bf16 (low 16)
    unsigned u = __float_as_uint(f);
    return (u + 0x7fffu + ((u >> 16) & 1u)) >> 16;
}
__device__ __forceinline__ float bf2f(unsigned s) {       // bf16(low16)->f32
    return __uint_as_float(s << 16);
}

// ----------------- f32 register-tile GEMM helper (VALU path) ---------------
template<int K, int KP, int NOUT>
__device__ __forceinline__ void gemm_tile_phase(const float* in_lds,
                                                const float* __restrict__ W,
                                                const float* __restrict__ b,
                                                float acc[4][4], int jq, int rg) {
    #pragma unroll
    for (int c = 0; c < 4; ++c) {
        float bv = b[jq + c];
        acc[0][c] = bv; acc[1][c] = bv; acc[2][c] = bv; acc[3][c] = bv;
    }
    int k = 0;
    for (; k + 4 <= K; k += 4) {
        float4 w0 = *(const float4*)&W[(k + 0) * NOUT + jq];
        float4 w1 = *(const float4*)&W[(k + 1) * NOUT + jq];
        float4 w2 = *(const float4*)&W[(k + 2) * NOUT + jq];
        float4 w3 = *(const float4*)&W[(k + 3) * NOUT + jq];
        #pragma unroll
        for (int rr = 0; rr < 4; ++rr) {
            int row = rg + rr * 8;
            float4 xv = *(const float4*)&in_lds[row * KP + k];
            acc[rr][0] += xv.x * w0.x + xv.y * w1.x + xv.z * w2.x + xv.w * w3.x;
            acc[rr][1] += xv.x * w0.y + xv.y * w1.y + xv.z * w2.y + xv.w * w3.y;
            acc[rr][2] += xv.x * w0.z + xv.y * w1.z + xv.z * w2.z + xv.w * w3.z;
            acc[rr][3] += xv.x * w0.w + xv.y * w1.w + xv.z * w2.w + xv.w * w3.w;
        }
    }
    for (; k < K; ++k) {
        float4 w0 = *(const float4*)&W[k * NOUT + jq];
        #pragma unroll
        for (int rr = 0; rr < 4; ++rr) {
            float xv = in_lds[(rg + rr * 8) * KP + k];
            acc[rr][0] += xv * w0.x;
            acc[rr][1] += xv * w0.y;
            acc[rr][2] += xv * w0.z;
            acc[rr][3] += xv * w0.w;
        }
    }
}

__device__ __forceinline__ float4 relu4(const float a[4]) {
    return make_float4(fmaxf(a[0], 0.f), fmaxf(a[1], 0.f),
                       fmaxf(a[2], 0.f), fmaxf(a[3], 0.f));
}

// ----------------------------- node encoder -------------------------------
__global__ __launch_bounds__(256) void node_enc_kernel(
    const float* __restrict__ x, const float* __restrict__ coords,
    const float* __restrict__ W1, const float* __restrict__ b1,
    const float* __restrict__ W2, const float* __restrict__ b2,
    float* __restrict__ h, u16* __restrict__ h_bf, int N_) {
    __shared__ float in9[TILE * 12];
    __shared__ float hid[TILE * 128];
    int t = threadIdx.x;
    int n0 = blockIdx.x * TILE;
    for (int i = t; i < TILE * 12; i += 256) {
        int r = i / 12, k = i % 12;
        int n = min(n0 + r, N_ - 1);
        float v = 0.f;
        if (k < 3) v = coords[n * 3 + k];
        else if (k < 9) v = x[n * 9 + k];
        in9[i] = v;
    }
    __syncthreads();
    int jq = (t & 31) * 4, rg = t >> 5;
    float acc[4][4];
    gemm_tile_phase<9, 12, 128>(in9, W1, b1, acc, jq, rg);
    #pragma unroll
    for (int rr = 0; rr < 4; ++rr)
        *(float4*)&hid[(rg + rr * 8) * 128 + jq] = relu4(acc[rr]);
    __syncthreads();
    gemm_tile_phase<128, 128, 128>(hid, W2, b2, acc, jq, rg);
    #pragma unroll
    for (int rr = 0; rr < 4; ++rr) {
        int n = n0 + rg + rr * 8;
        if (n < N_) {
            *(float4*)&h[(size_t)n * 128 + jq] =
                make_float4(acc[rr][0], acc[rr][1], acc[rr][2], acc[rr][3]);
            if (h_bf) {
                unsigned p0 = f2bf(acc[rr][0]) | (f2bf(acc[rr][1]) << 16);
                unsigned p1 = f2bf(acc[rr][2]) | (f2bf(acc[rr][3]) << 16);
                *(uint2*)&h_bf[(size_t)n * 128 + jq] = make_uint2(p0, p1);
            }
        }
    }
}

// ------------------- edge encoder (f32 VALU, bf16 out; tier<=2) ------------
__global__ __launch_bounds__(256) void edge_enc_bf16_kernel(
    const float* __restrict__ ea,
    const float* __restrict__ W1, const float* __restrict__ b1,
    const float* __restrict__ W2, const float* __restrict__ b2,
    u16* __restrict__ e, int E_) {
    __shared__ float in10[TILE * 12];
    __shared__ float hid[TILE * 128];
    int t = threadIdx.x;
    int e0 = blockIdx.x * TILE;
    for (int i = t; i < TILE * 12; i += 256) {
        int r = i / 12, k = i % 12;
        int eg = min(e0 + r, E_ - 1);
        in10[i] = (k < 10) ? ea[(size_t)eg * 10 + k] : 0.f;
    }
    __syncthreads();
    int jq = (t & 31) * 4, rg = t >> 5;
    float acc[4][4];
    gemm_tile_phase<10, 12, 128>(in10, W1, b1, acc, jq, rg);
    #pragma unroll
    for (int rr = 0; rr < 4; ++rr)
        *(float4*)&hid[(rg + rr * 8) * 128 + jq] = relu4(acc[rr]);
    __syncthreads();
    gemm_tile_phase<128, 128, 128>(hid, W2, b2, acc, jq, rg);
    #pragma unroll
    for (int rr = 0; rr < 4; ++rr) {
        int eg = e0 + rg + rr * 8;
        if (eg < E_) {
            unsigned p0 = f2bf(acc[rr][0]) | (f2bf(acc[rr][1]) << 16);
            unsigned p1 = f2bf(acc[rr][2]) | (f2bf(acc[rr][3]) << 16);
            *(uint2*)&e[(size_t)eg * 128 + jq] = make_uint2(p0, p1);
        }
    }
}

// ---------- weight prep: f32 stacked [L][K][N] -> bf16^T [L][N][Kp] --------
__global__ __launch_bounds__(256) void wt_stacked_kernel(
    const float* __restrict__ W, u16* __restrict__ Wt,
    int Lc, int K, int Kp, int Nn) {
    size_t i = (size_t)blockIdx.x * 256 + threadIdx.x;
    size_t tot = (size_t)Lc * Nn * Kp;
    if (i >= tot) return;
    int k = (int)(i % Kp);
    size_t r = i / Kp;
    int n = (int)(r % Nn);
    int l = (int)(r / Nn);
    Wt[i] = (k < K) ? (u16)f2bf(W[((size_t)l * K + k) * Nn + n]) : (u16)0;
}

// --------------------------- counting sort by dst --------------------------
__global__ __launch_bounds__(256) void hist_kernel(
    const int* __restrict__ dst, int* __restrict__ cnt, int E_) {
    int i = blockIdx.x * 256 + threadIdx.x;
    if (i < E_) atomicAdd(&cnt[dst[i]], 1);
}

__global__ __launch_bounds__(1024) void scan_kernel(
    const int* __restrict__ cnt, int* __restrict__ row_ptr, int n) {
    __shared__ int sums[1024];
    int t = threadIdx.x;
    int per = (n + 1023) / 1024;
    int lo = t * per, hi = min(lo + per, n);
    int s = 0;
    for (int i = lo; i < hi; ++i) s += cnt[i];
    sums[t] = s;
    __syncthreads();
    for (int d = 1; d < 1024; d <<= 1) {
        int v = (t >= d) ? sums[t - d] : 0;
        __syncthreads();
        sums[t] += v;
        __syncthreads();
    }
    int run = sums[t] - s;   // exclusive prefix of this chunk
    for (int i = lo; i < hi; ++i) { row_ptr[i] = run; run += cnt[i]; }
    if (t == 1023) row_ptr[n] = run;
}

__global__ __launch_bounds__(256) void scatter_kernel(
    const int* __restrict__ src, const int* __restrict__ dst,
    const int* __restrict__ row_ptr, int* __restrict__ fill,
    int* __restrict__ src_s, int* __restrict__ dst_s, int* __restrict__ permE,
    int E_) {
    int i = blockIdx.x * 256 + threadIdx.x;
    if (i >= E_) return;
    int d = dst[i];
    int pos = row_ptr[d] + atomicAdd(&fill[d], 1);
    src_s[pos] = src[i];
    dst_s[pos] = d;
    permE[pos] = i;
}

// ------------------- edge encoder (bf16 MFMA, tier 3) ----------------------
__global__ __launch_bounds__(256) void edge_enc_mfma_kernel(
    const float* __restrict__ ea,
    const u16* __restrict__ W1t,   // [128][16], k-padded
    const float* __restrict__ b1,
    const u16* __restrict__ W2t,   // [128][128]
    const float* __restrict__ b2,
    u16* __restrict__ e_bf, int E_) {
    __shared__ __align__(16) u16 A1[128 * 16];
    __shared__ __align__(16) u16 Hs[128 * 136];   // hidden; reused as C
    int t = threadIdx.x;
    int e0 = blockIdx.x * 128;
    for (int i = t; i < 128 * 16; i += 256) {
        int r = i >> 4, k = i & 15;
        int eg = min(e0 + r, E_ - 1);
        A1[i] = (k < 10) ? (u16)f2bf(ea[(size_t)eg * 10 + k]) : (u16)0;
    }
    __syncthreads();

    const int w = t >> 6, lane = t & 63;
    const int wm = w >> 1, wn = w & 1;
    const int l31 = lane & 31, lhi = lane >> 5;

    const u16* pb1[2];
    const u16* pb2[2];
    #pragma unroll
    for (int nf = 0; nf < 2; ++nf) {
        int n = wn * 64 + nf * 32 + l31;
        pb1[nf] = W1t + (size_t)n * 16;
        pb2[nf] = W2t + (size_t)n * 128;
    }

    f32x16 acc[2][2];
    #pragma unroll
    for (int nf = 0; nf < 2; ++nf) {
        float bv = b1[wn * 64 + nf * 32 + l31];
        #pragma unroll
        for (int mf = 0; mf < 2; ++mf)
            #pragma unroll
            for (int q = 0; q < 16; ++q) acc[mf][nf][q] = bv;
    }
    // GEMM1: K=16 (single step); A from LDS, B direct from global
    {
        bf16x8 av[2], bv[2];
        #pragma unroll
        for (int mf = 0; mf < 2; ++mf)
            av[mf] = *reinterpret_cast<const bf16x8*>(
                &A1[(wm * 64 + mf * 32 + l31) * 16 + lhi * 8]);
        #pragma unroll
        for (int nf = 0; nf < 2; ++nf)
            bv[nf] = *reinterpret_cast<const bf16x8*>(pb1[nf] + lhi * 8);
        #pragma unroll
        for (int mf = 0; mf < 2; ++mf)
            #pragma unroll
            for (int nf = 0; nf < 2; ++nf)
                acc[mf][nf] = __builtin_amdgcn_mfma_f32_32x32x16_bf16(
                    av[mf], bv[nf], acc[mf][nf], 0, 0, 0);
    }
    // ReLU -> Hs
    #pragma unroll
    for (int mf = 0; mf < 2; ++mf)
        #pragma unroll
        for (int nf = 0; nf < 2; ++nf) {
            int colbase = wn * 64 + nf * 32 + l31;
            int rowbase = wm * 64 + mf * 32 + 4 * lhi;
            #pragma unroll
            for (int q = 0; q < 16; ++q) {
                int row = rowbase + (q & 3) + 8 * (q >> 2);
                Hs[row * 136 + colbase] = (u16)f2bf(fmaxf(acc[mf][nf][q], 0.f));
            }
        }
    #pragma unroll
    for (int nf = 0; nf < 2; ++nf) {
        float bv = b2[wn * 64 + nf * 32 + l31];
        #pragma unroll
        for (int mf = 0; mf < 2; ++mf)
            #pragma unroll
            for (int q = 0; q < 16; ++q) acc[mf][nf][q] = bv;
    }
    __syncthreads();
    // GEMM2: K=128, A from Hs, B direct from global
    #pragma unroll
    for (int kc = 0; kc < 8; ++kc) {
        int ko = kc * 16 + lhi * 8;
        bf16x8 av[2], bv[2];
        #pragma unroll
        for (int mf = 0; mf < 2; ++mf)
            av[mf] = *reinterpret_cast<const bf16x8*>(
                &Hs[(wm * 64 + mf * 32 + l31) * 136 + ko]);
        #pragma unroll
        for (int nf = 0; nf < 2; ++nf)
            bv[nf] = *reinterpret_cast<const bf16x8*>(pb2[nf] + ko);
        #pragma unroll
        for (int mf = 0; mf < 2; ++mf)
            #pragma unroll
            for (int nf = 0; nf < 2; ++nf)
                acc[mf][nf] = __builtin_amdgcn_mfma_f32_32x32x16_bf16(
                    av[mf], bv[nf], acc[mf][nf], 0, 0, 0);
    }
    // C overlay -> coalesced store
    __syncthreads();
    u16* C = Hs;
    #pragma unroll
    for (int mf = 0; mf < 2; ++mf)
        #pragma unroll
        for (int nf = 0; nf < 2; ++nf) {
            int colbase = wn * 64 + nf * 32 + l31;
            int rowbase = wm * 64 + mf * 32 + 4 * lhi;
            #pragma unroll
            for (int q = 0; q < 16; ++q) {
                int row = rowbase + (q & 3) + 8 * (q >> 2);
                C[row * 136 + colbase] = (u16)f2bf(acc[mf][nf][q]);
            }
        }
    __syncthreads();
    for (int i = t; i < 128 * 32; i += 256) {
        int r = i >> 5, c4 = (i & 31) * 4;
        if (e0 + r < E_)
            *(uint2*)&e_bf[(size_t)(e0 + r) * 128 + c4] = *(uint2*)&C[r * 136 + c4];
    }
}

// ---- edge message + segmented scatter (LDS-A dbuf + direct-B, tier 3) -----
__global__ __launch_bounds__(256, 4) void edge_mp_sorted_kernel(
    const u16* __restrict__ h_bf, const u16* __restrict__ e_bf,
    const int* __restrict__ src_s, const int* __restrict__ dst_s,
    const int* __restrict__ permE,
    const u16* __restrict__ W1t, const float* __restrict__ b1,
    const u16* __restrict__ W2t, const float* __restrict__ b2,
    float* __restrict__ agg, int E_) {
    // 34KB buffer: during GEMM1 its first 20KB is the A double-buffer;
    // afterwards it holds hidden [128][136] and then the C tile.
    __shared__ __align__(16) u16 Hs[128 * 136];
    __shared__ int idx_s[3 * 128];                 // src | dst | perm
    u16* Ab0 = Hs;
    u16* Ab1 = Hs + 128 * 40;

    int t = threadIdx.x;
    int e0 = blockIdx.x * 128;
    if (t < 128) {
        int pp = min(e0 + t, E_ - 1);
        idx_s[t]       = src_s[pp];
        idx_s[128 + t] = dst_s[pp];
        idx_s[256 + t] = permE[pp];
    }
    __syncthreads();   // idx_s visible for staging

    const int w = t >> 6, lane = t & 63;
    const int wm = w >> 1, wn = w & 1;
    const int l31 = lane & 31, lhi = lane >> 5;

    const int sr0 = t >> 2, sch = t & 3;           // staging coords (2 chunks)
    const int sr1 = sr0 + 64;

    const u16* pb1[2];
    const u16* pb2[2];
    #pragma unroll
    for (int nf = 0; nf < 2; ++nf) {
        int n = wn * 64 + nf * 32 + l31;
        pb1[nf] = W1t + (size_t)n * 384;
        pb2[nf] = W2t + (size_t)n * 128;
    }

    auto STAGE = [&](u16* buf, int s) {
        int reg = s >> 2;              // 0: h[src], 1: h[dst], 2: e
        int kc0 = (s & 3) * 32;        // k offset within 128-wide region
        const u16* b0;
        const u16* b1p;
        if (reg == 0)      { b0 = h_bf + (size_t)idx_s[sr0] * 128;
                             b1p = h_bf + (size_t)idx_s[sr1] * 128; }
        else if (reg == 1) { b0 = h_bf + (size_t)idx_s[128 + sr0] * 128;
                             b1p = h_bf + (size_t)idx_s[128 + sr1] * 128; }
        else               { b0 = e_bf + (size_t)idx_s[256 + sr0] * 128;
                             b1p = e_bf + (size_t)idx_s[256 + sr1] * 128; }
        *(ushort8*)&buf[sr0 * 40 + sch * 8] = *(const ushort8*)(b0 + kc0 + sch * 8);
        *(ushort8*)&buf[sr1 * 40 + sch * 8] = *(const ushort8*)(b1p + kc0 + sch * 8);
    };

    f32x16 acc[2][2];
    #pragma unroll
    for (int nf = 0; nf < 2; ++nf) {
        float bv = b1[wn * 64 + nf * 32 + l31];
        #pragma unroll
        for (int mf = 0; mf < 2; ++mf)
            #pragma unroll
            for (int q = 0; q < 16; ++q) acc[mf][nf][q] = bv;
    }

    // -------- GEMM1: K=384, A double-buffered in LDS, B direct global ------
    STAGE(Ab0, 0);
    __syncthreads();
    for (int s = 0; s < 12; ++s) {
        u16* cur = (s & 1) ? Ab1 : Ab0;
        if (s < 11) STAGE((s & 1) ? Ab0 : Ab1, s + 1);
        #pragma unroll
        for (int kh = 0; kh < 2; ++kh) {
            int ko = kh * 16 + lhi * 8;
            bf16x8 av[2], bv[2];
            #pragma unroll
            for (int mf = 0; mf < 2; ++mf)
                av[mf] = *reinterpret_cast<const bf16x8*>(
                    &cur[(wm * 64 + mf * 32 + l31) * 40 + ko]);
            #pragma unroll
            for (int nf = 0; nf < 2; ++nf)
                bv[nf] = *reinterpret_cast<const bf16x8*>(pb1[nf] + s * 32 + ko);
            #pragma unroll
            for (int mf = 0; mf < 2; ++mf)
                #pragma unroll
                for (int nf = 0; nf < 2; ++nf)
                    acc[mf][nf] = __builtin_amdgcn_mfma_f32_32x32x16_bf16(
                        av[mf], bv[nf], acc[mf][nf], 0, 0, 0);
        }
        __syncthreads();
    }

    // -------- ReLU + bf16 -> Hs (overwrites the A dbuf region) -------------
    #pragma unroll
    for (int mf = 0; mf < 2; ++mf)
        #pragma unroll
        for (int nf = 0; nf < 2; ++nf) {
            int colbase = wn * 64 + nf * 32 + l31;
            int rowbase = wm * 64 + mf * 32 + 4 * lhi;
            #pragma unroll
            for (int q = 0; q < 16; ++q) {
                int row = rowbase + (q & 3) + 8 * (q >> 2);
                Hs[row * 136 + colbase] = (u16)f2bf(fmaxf(acc[mf][nf][q], 0.f));
            }
        }
    #pragma unroll
    for (int nf = 0; nf < 2; ++nf) {
        float bv = b2[wn * 64 + nf * 32 + l31];
        #pragma unroll
        for (int mf = 0; mf < 2; ++mf)
            #pragma unroll
            for (int q = 0; q < 16; ++q) acc[mf][nf][q] = bv;
    }
    __syncthreads();

    // -------- GEMM2: K=128, A from Hs, B direct global, 0 barriers ---------
    #pragma unroll
    for (int kc = 0; kc < 8; ++kc) {
        int ko = kc * 16 + lhi * 8;
        bf16x8 av[2], bv[2];
        #pragma unroll
        for (int mf = 0; mf < 2; ++mf)
            av[mf] = *reinterpret_cast<const bf16x8*>(
                &Hs[(wm * 64 + mf * 32 + l31) * 136 + ko]);
        #pragma unroll
        for (int nf = 0; nf < 2; ++nf)
            bv[nf] = *reinterpret_cast<const bf16x8*>(pb2[nf] + ko);
        #pragma unroll
        for (int mf = 0; mf < 2; ++mf)
            #pragma unroll
            for (int nf = 0; nf < 2; ++nf)
                acc[mf][nf] = __builtin_amdgcn_mfma_f32_32x32x16_bf16(
                    av[mf], bv[nf], acc[mf][nf], 0, 0, 0);
    }

    // -------- C -> LDS (overlay Hs), segmented reduce, few atomics ---------
    __syncthreads();   // all Hs reads done
    u16* C = Hs;       // stride 136
    #pragma unroll
    for (int mf = 0; mf < 2; ++mf)
        #pragma unroll
        for (int nf = 0; nf < 2; ++nf) {
            int colbase = wn * 64 + nf * 32 + l31;
            int rowbase = wm * 64 + mf * 32 + 4 * lhi;
            #pragma unroll
            for (int q = 0; q < 16; ++q) {
                int row = rowbase + (q & 3) + 8 * (q >> 2);
                C[row * 136 + colbase] = (u16)f2bf(acc[mf][nf][q]);
            }
        }
    __syncthreads();
    {
        int col = t & 127, seg = t >> 7;
        int r0 = seg * 64, r1 = r0 + 64;
        float s = 0.f; int cur = -1;
        for (int r = r0; r < r1; ++r) {
            if (e0 + r >= E_) break;
            int d = idx_s[128 + r];
            float v = bf2f(C[r * 136 + col]);
            if (d != cur) {
                if (cur >= 0) unsafeAtomicAdd(&agg[(size_t)cur * 128 + col], s);
                cur = d; s = v;
            } else s += v;
        }
        if (cur >= 0) unsafeAtomicAdd(&agg[(size_t)cur * 128 + col], s);
    }
}

// ------ node update (LDS-A dbuf + direct-B MFMA + residual, tier 3) --------
__global__ __launch_bounds__(256, 4) void node_mp_mfma_kernel(
    float* __restrict__ h, u16* __restrict__ h_bf,
    const float* __restrict__ agg,
    const u16* __restrict__ W1t, const float* __restrict__ b1,
    const u16* __restrict__ W2t, const float* __restrict__ b2, int N_) {
    __shared__ __align__(16) u16 Hs[128 * 136];
    u16* Ab0 = Hs;
    u16* Ab1 = Hs + 128 * 40;
    int t = threadIdx.x;
    int n0 = blockIdx.x * 128;

    const int w = t >> 6, lane = t & 63;
    const int wm = w >> 1, wn = w & 1;
    const int l31 = lane & 31, lhi = lane >> 5;

    const int sr0 = t >> 2, sch = t & 3;
    const int sr1 = sr0 + 64;
    const int gn0 = min(n0 + sr0, N_ - 1);
    const int gn1 = min(n0 + sr1, N_ - 1);

    const u16* pb1[2];
    const u16* pb2[2];
    #pragma unroll
    for (int nf = 0; nf < 2; ++nf) {
        int n = wn * 64 + nf * 32 + l31;
        pb1[nf] = W1t + (size_t)n * 256;
        pb2[nf] = W2t + (size_t)n * 128;
    }

    auto CVT = [&](const float* ap) {
        float4 a0 = *(const float4*)ap;
        float4 a1 = *(const float4*)(ap + 4);
        ushort8 v;
        v[0] = (u16)f2bf(a0.x); v[1] = (u16)f2bf(a0.y);
        v[2] = (u16)f2bf(a0.z); v[3] = (u16)f2bf(a0.w);
        v[4] = (u16)f2bf(a1.x); v[5] = (u16)f2bf(a1.y);
        v[6] = (u16)f2bf(a1.z); v[7] = (u16)f2bf(a1.w);
        return v;
    };

    auto STAGE = [&](u16* buf, int s) {
        int kc0 = (s & 3) * 32;
        if (s < 4) {
            *(ushort8*)&buf[sr0 * 40 + sch * 8] =
                *(const ushort8*)(h_bf + (size_t)gn0 * 128 + kc0 + sch * 8);
            *(ushort8*)&buf[sr1 * 40 + sch * 8] =
                *(const ushort8*)(h_bf + (size_t)gn1 * 128 + kc0 + sch * 8);
        } else {
            *(ushort8*)&buf[sr0 * 40 + sch * 8] =
                CVT(agg + (size_t)gn0 * 128 + kc0 + sch * 8);
            *(ushort8*)&buf[sr1 * 40 + sch * 8] =
                CVT(agg + (size_t)gn1 * 128 + kc0 + sch * 8);
        }
    };

    f32x16 acc[2][2];
    #pragma unroll
    for (int nf = 0; nf < 2; ++nf) {
        float bv = b1[wn * 64 + nf * 32 + l31];
        #pragma unroll
        for (int mf = 0; mf < 2; ++mf)
            #pragma unroll
            for (int q = 0; q < 16; ++q) acc[mf][nf][q] = bv;
    }

    // -------- GEMM1: K=256 (h_bf | agg), A dbuf in LDS, B direct -----------
    STAGE(Ab0, 0);
    __syncthreads();
    for (int s = 0; s < 8; ++s) {
        u16* cur = (s & 1) ? Ab1 : Ab0;
        if (s < 7) STAGE((s & 1) ? Ab0 : Ab1, s + 1);
        #pragma unroll
        for (int kh = 0; kh < 2; ++kh) {
            int ko = kh * 16 + lhi * 8;
            bf16x8 av[2], bv[2];
            #pragma unroll
            for (int mf = 0; mf < 2; ++mf)
                av[mf] = *reinterpret_cast<const bf16x8*>(
                    &cur[(wm * 64 + mf * 32 + l31) * 40 + ko]);
            #pragma unroll
            for (int nf = 0; nf < 2; ++nf)
                bv[nf] = *reinterpret_cast<const bf16x8*>(pb1[nf] + s * 32 + ko);
            #pragma unroll
            for (int mf = 0; mf < 2; ++mf)
                #pragma unroll
                for (int nf = 0; nf < 2; ++nf)
                    acc[mf][nf] = __builtin_amdgcn_mfma_f32_32x32x16_bf16(
                        av[mf], bv[nf], acc[mf][nf], 0, 0, 0);
        }
        __syncthreads();
    }

    // -------- ReLU -> Hs --------
    #pragma unroll
    for (int mf = 0; mf < 2; ++mf)
        #pragma unroll
        for (int nf = 0; nf < 2; ++nf) {
            int colbase = wn * 64 + nf * 32 + l31;
            int rowbase = wm * 64 + mf * 32 + 4 * lhi;
            #pragma unroll
            for (int q = 0; q < 16; ++q) {
                int row = rowbase + (q & 3) + 8 * (q >> 2);
                Hs[row * 136 + colbase] = (u16)f2bf(fmaxf(acc[mf][nf][q], 0.f));
            }
        }
    #pragma unroll
    for (int nf = 0; nf < 2; ++nf) {
        float bv = b2[wn * 64 + nf * 32 + l31];
        #pragma unroll
        for (int mf = 0; mf < 2; ++mf)
            #pragma unroll
            for (int q = 0; q < 16; ++q) acc[mf][nf][q] = bv;
    }
    __syncthreads();

    // -------- GEMM2: K=128, A from Hs, B direct --------
    #pragma unroll
    for (int kc = 0; kc < 8; ++kc) {
        int ko = kc * 16 + lhi * 8;
        bf16x8 av[2], bv[2];
        #pragma unroll
        for (int mf = 0; mf < 2; ++mf)
            av[mf] = *reinterpret_cast<const bf16x8*>(
                &Hs[(wm * 64 + mf * 32 + l31) * 136 + ko]);
        #pragma unroll
        for (int nf = 0; nf < 2; ++nf)
            bv[nf] = *reinterpret_cast<const bf16x8*>(pb2[nf] + ko);
        #pragma unroll
        for (int mf = 0; mf < 2; ++mf)
            #pragma unroll
            for (int nf = 0; nf < 2; ++nf)
                acc[mf][nf] = __builtin_amdgcn_mfma_f32_32x32x16_bf16(
                    av[mf], bv[nf], acc[mf][nf], 0, 0, 0);
    }

    // -------- C -> LDS, residual epilogue (coalesced) --------
    __syncthreads();
    u16* C = Hs;
    #pragma unroll
    for (int mf = 0; mf < 2; ++mf)
        #pragma unroll
        for (int nf = 0; nf < 2; ++nf) {
            int colbase = wn * 64 + nf * 32 + l31;
            int rowbase = wm * 64 + mf * 32 + 4 * lhi;
            #pragma unroll
            for (int q = 0; q < 16; ++q) {
                int row = rowbase + (q & 3) + 8 * (q >> 2);
                C[row * 136 + colbase] = (u16)f2bf(acc[mf][nf][q]);
            }
        }
    __syncthreads();
    for (int i = t; i < 128 * 32; i += 256) {
        int r = i >> 5, c4 = (i & 31) * 4;
        int n = n0 + r;
        if (n < N_) {
            float4 hv = *(const float4*)&h[(size_t)n * 128 + c4];
            hv.x += bf2f(C[r * 136 + c4 + 0]);
            hv.y += bf2f(C[r * 136 + c4 + 1]);
            hv.z += bf2f(C[r * 136 + c4 + 2]);
            hv.w += bf2f(C[r * 136 + c4 + 3]);
            *(float4*)&h[(size_t)n * 128 + c4] = hv;
            unsigned p0 = f2bf(hv.x) | (f2bf(hv.y) << 16);
            unsigned p1 = f2bf(hv.z) | (f2bf(hv.w) << 16);
            *(uint2*)&h_bf[(size_t)n * 128 + c4] = make_uint2(p0, p1);
        }
    }
}

// ------------- edge message + scatter: bf16 MFMA (tier 2 fallback) ---------
__global__ __launch_bounds__(256) void edge_mp_mfma_kernel(
    const u16* __restrict__ h_bf, const u16* __restrict__ e_bf,
    const int* __restrict__ src, const int* __restrict__ dst,
    const u16* __restrict__ W1t, const float* __restrict__ b1,
    const u16* __restrict__ W2t, const float* __restrict__ b2,
    float* __restrict__ agg, int E_) {
    __shared__ __align__(16) u16 A1[128 * 40];
    __shared__ __align__(16) u16 Bl[128 * 40];
    __shared__ __align__(16) u16 A2[128 * 136];
    __shared__ int idx_s[256];
    int t = threadIdx.x;
    int e0 = blockIdx.x * 128;
    if (t < 128) idx_s[t] = src[min(e0 + t, E_ - 1)];
    else         idx_s[t] = dst[min(e0 + t - 128, E_ - 1)];
    __syncthreads();

    const int w = t >> 6, lane = t & 63;
    const int wm = w >> 1, wn = w & 1;
    const int l31 = lane & 31, lhi = lane >> 5;

    f32x16 acc[2][2];
    #pragma unroll
    for (int nf = 0; nf < 2; ++nf) {
        float bv = b1[wn * 64 + nf * 32 + l31];
        #pragma unroll
        for (int mf = 0; mf < 2; ++mf)
            #pragma unroll
            for (int q = 0; q < 16; ++q) acc[mf][nf][q] = bv;
    }
    for (int s = 0; s < 12; ++s) {
        int ks = s * 32;
        #pragma unroll
        for (int cc = 0; cc < 2; ++cc) {
            int c = t + cc * 256;
            int r = c >> 2, ch = c & 3;
            int kcol = (ks & 127) + ch * 8;
            const u16* sp;
            if (ks < 128)      sp = h_bf + (size_t)idx_s[r] * 128 + kcol;
            else if (ks < 256) sp = h_bf + (size_t)idx_s[128 + r] * 128 + kcol;
            else               sp = e_bf + (size_t)min(e0 + r, E_ - 1) * 128 + kcol;
            *(ushort8*)&A1[r * 40 + ch * 8] = *(const ushort8*)sp;
        }
        #pragma unroll
        for (int cc = 0; cc < 2; ++cc) {
            int c = t + cc * 256;
            int n = c >> 2, ch = c & 3;
            *(ushort8*)&Bl[n * 40 + ch * 8] =
                *(const ushort8*)&W1t[(size_t)n * 384 + ks + ch * 8];
        }
        __syncthreads();
        #pragma unroll
        for (int kh = 0; kh < 2; ++kh) {
            int koff = kh * 16 + lhi * 8;
            bf16x8 av[2], bv[2];
            #pragma unroll
            for (int mf = 0; mf < 2; ++mf)
                av[mf] = *reinterpret_cast<const bf16x8*>(
                    &A1[(wm * 64 + mf * 32 + l31) * 40 + koff]);
            #pragma unroll
            for (int nf = 0; nf < 2; ++nf)
                bv[nf] = *reinterpret_cast<const bf16x8*>(
                    &Bl[(wn * 64 + nf * 32 + l31) * 40 + koff]);
            #pragma unroll
            for (int mf = 0; mf < 2; ++mf)
                #pragma unroll
                for (int nf = 0; nf < 2; ++nf)
                    acc[mf][nf] = __builtin_amdgcn_mfma_f32_32x32x16_bf16(
                        av[mf], bv[nf], acc[mf][nf], 0, 0, 0);
        }
        __syncthreads();
    }
    #pragma unroll
    for (int mf = 0; mf < 2; ++mf)
        #pragma unroll
        for (int nf = 0; nf < 2; ++nf) {
            int colbase = wn * 64 + nf * 32 + l31;
            int rowbase = wm * 64 + mf * 32 + 4 * lhi;
            #pragma unroll
            for (int q = 0; q < 16; ++q) {
                int row = rowbase + (q & 3) + 8 * (q >> 2);
                A2[row * 136 + colbase] = (u16)f2bf(fmaxf(acc[mf][nf][q], 0.f));
            }
        }
    #pragma unroll
    for (int nf = 0; nf < 2; ++nf) {
        float bv = b2[wn * 64 + nf * 32 + l31];
        #pragma unroll
        for (int mf = 0; mf < 2; ++mf)
            #pragma unroll
            for (int q = 0; q < 16; ++q) acc[mf][nf][q] = bv;
    }
    for (int s = 0; s < 4; ++s) {
        int ks = s * 32;
        __syncthreads();
        #pragma unroll
        for (int cc = 0; cc < 2; ++cc) {
            int c = t + cc * 256;
            int n = c >> 2, ch = c & 3;
            *(ushort8*)&Bl[n * 40 + ch * 8] =
                *(const ushort8*)&W2t[(size_t)n * 128 + ks + ch * 8];
        }
        __syncthreads();
        #pragma unroll
        for (int kh = 0; kh < 2; ++kh) {
            int koff = kh * 16 + lhi * 8;
            bf16x8 av[2], bv[2];
            #pragma unroll
            for (int mf = 0; mf < 2; ++mf)
                av[mf] = *reinterpret_cast<const bf16x8*>(
                    &A2[(wm * 64 + mf * 32 + l31) * 136 + ks + koff]);
            #pragma unroll
            for (int nf = 0; nf < 2; ++nf)
                bv[nf] = *reinterpret_cast<const bf16x8*>(
                    &Bl[(wn * 64 + nf * 32 + l31) * 40 + koff]);
            #pragma unroll
            for (int mf = 0; mf < 2; ++mf)
                #pragma unroll
                for (int nf = 0; nf < 2; ++nf)
                    acc[mf][nf] = __builtin_amdgcn_mfma_f32_32x32x16_bf16(
                        av[mf], bv[nf], acc[mf][nf], 0, 0, 0);
        }
    }
    #pragma unroll
    for (int mf = 0; mf < 2; ++mf)
        #pragma unroll
        for (int nf = 0; nf < 2; ++nf) {
            int colbase = wn * 64 + nf * 32 + l31;
            int rowbase = wm * 64 + mf * 32 + 4 * lhi;
            #pragma unroll
            for (int q = 0; q < 16; ++q) {
                int row = rowbase + (q & 3) + 8 * (q >> 2);
                if (e0 + row < E_)
                    unsafeAtomicAdd(&agg[(size_t)idx_s[128 + row] * 128 + colbase],
                                    acc[mf][nf][q]);
            }
        }
}

// ------------- edge message + scatter (tier 1: f32 VALU) -------------------
__global__ __launch_bounds__(256) void edge_mp_a_kernel(
    const float* __restrict__ h, const u16* __restrict__ e,
    const int* __restrict__ src, const int* __restrict__ dst,
    const float* __restrict__ W1, const float* __restrict__ b1,
    const float* __restrict__ W2, const float* __restrict__ b2,
    float* __restrict__ agg, int E_) {
    __shared__ float buf[TILE * 384];
    __shared__ int idx_s[2 * TILE];
    int t = threadIdx.x;
    int e0 = blockIdx.x * TILE;
    if (t < TILE) idx_s[t] = src[min(e0 + t, E_ - 1)];
    else if (t < 2 * TILE) idx_s[t] = dst[min(e0 + t - TILE, E_ - 1)];
    __syncthreads();
    for (int i = t; i < TILE * 96; i += 256) {
        int r = i / 96, col = (i % 96) * 4;
        float4 v;
        if (col < 128)      v = *(const float4*)&h[(size_t)idx_s[r] * 128 + col];
        else if (col < 256) v = *(const float4*)&h[(size_t)idx_s[TILE + r] * 128 + (col - 128)];
        else {
            uint2 u = *(const uint2*)&e[(size_t)min(e0 + r, E_ - 1) * 128 + (col - 256)];
            v = make_float4(bf2f(u.x & 0xffffu), bf2f(u.x >> 16),
                            bf2f(u.y & 0xffffu), bf2f(u.y >> 16));
        }
        *(float4*)&buf[r * 384 + col] = v;
    }
    __syncthreads();
    int jq = (t & 31) * 4, rg = t >> 5;
    float acc[4][4];
    gemm_tile_phase<384, 384, 128>(buf, W1, b1, acc, jq, rg);
    __syncthreads();
    #pragma unroll
    for (int rr = 0; rr < 4; ++rr)
        *(float4*)&buf[(rg + rr * 8) * 128 + jq] = relu4(acc[rr]);
    __syncthreads();
    gemm_tile_phase<128, 128, 128>(buf, W2, b2, acc, jq, rg);
    #pragma unroll
    for (int rr = 0; rr < 4; ++rr) {
        int row = rg + rr * 8;
        int eg = e0 + row;
        if (eg < E_) {
            float* dstp = &agg[(size_t)idx_s[TILE + row] * 128 + jq];
            unsafeAtomicAdd(dstp + 0, acc[rr][0]);
            unsafeAtomicAdd(dstp + 1, acc[rr][1]);
            unsafeAtomicAdd(dstp + 2, acc[rr][2]);
            unsafeAtomicAdd(dstp + 3, acc[rr][3]);
        }
    }
}

// ---------- edge message + scatter (tier 0: recompute encoder) -------------
__global__ __launch_bounds__(256) void edge_mp_b_kernel(
    const float* __restrict__ h, const float* __restrict__ ea,
    const int* __restrict__ src, const int* __restrict__ dst,
    const float* __restrict__ eW1, const float* __restrict__ eb1,
    const float* __restrict__ eW2, const float* __restrict__ eb2,
    const float* __restrict__ W1, const float* __restrict__ b1,
    const float* __restrict__ W2, const float* __restrict__ b2,
    float* __restrict__ agg, int E_) {
    __shared__ float buf[TILE * 384];
    __shared__ float in10[TILE * 12];
    __shared__ int idx_s[2 * TILE];
    int t = threadIdx.x;
    int e0 = blockIdx.x * TILE;
    if (t < TILE) idx_s[t] = src[min(e0 + t, E_ - 1)];
    else if (t < 2 * TILE) idx_s[t] = dst[min(e0 + t - TILE, E_ - 1)];
    for (int i = t; i < TILE * 12; i += 256) {
        int r = i / 12, k = i % 12;
        int eg = min(e0 + r, E_ - 1);
        in10[i] = (k < 10) ? ea[(size_t)eg * 10 + k] : 0.f;
    }
    __syncthreads();
    int jq = (t & 31) * 4, rg = t >> 5;
    float acc[4][4];
    gemm_tile_phase<10, 12, 128>(in10, eW1, eb1, acc, jq, rg);
    #pragma unroll
    for (int rr = 0; rr < 4; ++rr)
        *(float4*)&buf[(rg + rr * 8) * 384 + 128 + jq] = relu4(acc[rr]);
    __syncthreads();
    gemm_tile_phase<128, 384, 128>(buf + 128, eW2, eb2, acc, jq, rg);
    __syncthreads();
    #pragma unroll
    for (int rr = 0; rr < 4; ++rr)
        *(float4*)&buf[(rg + rr * 8) * 384 + 256 + jq] =
            make_float4(acc[rr][0], acc[rr][1], acc[rr][2], acc[rr][3]);
    __syncthreads();
    for (int i = t; i < TILE * 64; i += 256) {
        int r = i / 64, col = (i % 64) * 4;
        float4 v = (col < 128)
            ? *(const float4*)&h[(size_t)idx_s[r] * 128 + col]
            : *(const float4*)&h[(size_t)idx_s[TILE + r] * 128 + (col - 128)];
        *(float4*)&buf[r * 384 + col] = v;
    }
    __syncthreads();
    gemm_tile_phase<384, 384, 128>(buf, W1, b1, acc, jq, rg);
    __syncthreads();
    #pragma unroll
    for (int rr = 0; rr < 4; ++rr)
        *(float4*)&buf[(rg + rr * 8) * 128 + jq] = relu4(acc[rr]);
    __syncthreads();
    gemm_tile_phase<128, 128, 128>(buf, W2, b2, acc, jq, rg);
    #pragma unroll
    for (int rr = 0; rr < 4; ++rr) {
        int row = rg + rr * 8;
        int eg = e0 + row;
        if (eg < E_) {
            float* dstp = &agg[(size_t)idx_s[TILE + row] * 128 + jq];
            unsafeAtomicAdd(dstp + 0, acc[rr][0]);
            unsafeAtomicAdd(dstp + 1, acc[rr][1]);
            unsafeAtomicAdd(dstp + 2, acc[rr][2]);
            unsafeAtomicAdd(dstp + 3, acc[rr][3]);
        }
    }
}

// --------------------- node update (f32 VALU, tiers 0-2) -------------------
__global__ __launch_bounds__(256) void node_mp_kernel(
    float* __restrict__ h, u16* __restrict__ h_bf,
    const float* __restrict__ agg,
    const float* __restrict__ W1, const float* __restrict__ b1,
    const float* __restrict__ W2, const float* __restrict__ b2, int N_) {
    __shared__ float buf[TILE * 256];
    int t = threadIdx.x;
    int n0 = blockIdx.x * TILE;
    for (int i = t; i < TILE * 64; i += 256) {
        int r = i / 64, col = (i % 64) * 4;
        int n = min(n0 + r, N_ - 1);
        float4 v = (col < 128) ? *(const float4*)&h[(size_t)n * 128 + col]
                               : *(const float4*)&agg[(size_t)n * 128 + (col - 128)];
        *(float4*)&buf[r * 256 + col] = v;
    }
    __syncthreads();
    int jq = (t & 31) * 4, rg = t >> 5;
    float acc[4][4];
    gemm_tile_phase<256, 256, 128>(buf, W1, b1, acc, jq, rg);
    __syncthreads();
    #pragma unroll
    for (int rr = 0; rr < 4; ++rr)
        *(float4*)&buf[(rg + rr * 8) * 128 + jq] = relu4(acc[rr]);
    __syncthreads();
    gemm_tile_phase<128, 128, 128>(buf, W2, b2, acc, jq, rg);
    #pragma unroll
    for (int rr = 0; rr < 4; ++rr) {
        int n = n0 + rg + rr * 8;
        if (n < N_) {
            float4 old = *(const float4*)&h[(size_t)n * 128 + jq];
            old.x += acc[rr][0]; old.y += acc[rr][1];
            old.z += acc[rr][2]; old.w += acc[rr][3];
            *(float4*)&h[(size_t)n * 128 + jq] = old;
            if (h_bf) {
                unsigned p0 = f2bf(old.x) | (f2bf(old.y) << 16);
                unsigned p1 = f2bf(old.z) | (f2bf(old.w) << 16);
                *(uint2*)&h_bf[(size_t)n * 128 + jq] = make_uint2(p0, p1);
            }
        }
    }
}

// -------------------------------- decoder ---------------------------------
__global__ __launch_bounds__(256) void decoder_kernel(
    const float* __restrict__ h,
    const float* __restrict__ W1, const float* __restrict__ b1,
    const float* __restrict__ W2, const float* __restrict__ b2,
    const float* __restrict__ W3, const float* __restrict__ b3,
    const float* __restrict__ bc_disp, const float* __restrict__ bc_rot,
    float* __restrict__ out, int N_) {
    __shared__ float in_lds[TILE * 128];
    __shared__ float hid2[TILE * 64];
    int t = threadIdx.x;
    int n0 = blockIdx.x * TILE;
    for (int i = t; i < TILE * 32; i += 256) {
        int r = i / 32, col = (i % 32) * 4;
        int n = min(n0 + r, N_ - 1);
        *(float4*)&in_lds[r * 128 + col] = *(const float4*)&h[(size_t)n * 128 + col];
    }
    __syncthreads();
    int jq = (t & 31) * 4, rg = t >> 5;
    float acc[4][4];
    gemm_tile_phase<128, 128, 128>(in_lds, W1, b1, acc, jq, rg);
    __syncthreads();
    #pragma unroll
    for (int rr = 0; rr < 4; ++rr)
        *(float4*)&in_lds[(rg + rr * 8) * 128 + jq] = relu4(acc[rr]);
    __syncthreads();
    if ((t & 31) < 16) {
        float acc2[4][4];
        int jq2 = (t & 31) * 4;
        gemm_tile_phase<128, 128, 64>(in_lds, W2, b2, acc2, jq2, rg);
        #pragma unroll
        for (int rr = 0; rr < 4; ++rr)
            *(float4*)&hid2[(rg + rr * 8) * 64 + jq2] = relu4(acc2[rr]);
    }
    __syncthreads();
    if (t < TILE * 3) {
        int r = t / 3, c = t % 3;
        int n = n0 + r;
        if (n < N_) {
            float a = b3[c];
            for (int k = 0; k < 64; ++k) a += hid2[r * 64 + k] * W3[k * 3 + c];
            float m = (c == 2) ? (1.f - bc_rot[n]) : (1.f - bc_disp[n]);
            out[(size_t)n * 3 + c] = a * m;
        }
    }
}

// ------------------------------- launcher ----------------------------------
extern "C" void kernel_launch(void* const* d_in, const int* in_sizes, int n_in,
                              void* d_out, int out_size, void* d_ws, size_t ws_size,
                              hipStream_t stream) {
    const float* x        = (const float*)d_in[0];
    const float* coords   = (const float*)d_in[1];
    const float* ea       = (const float*)d_in[2];
    const int*   eidx     = (const int*)d_in[3];
    const float* bc_disp  = (const float*)d_in[4];
    const float* bc_rot   = (const float*)d_in[5];
    const float* enc_nW1  = (const float*)d_in[6];
    const float* enc_nb1  = (const float*)d_in[7];
    const float* enc_nW2  = (const float*)d_in[8];
    const float* enc_nb2  = (const float*)d_in[9];
    const float* enc_eW1  = (const float*)d_in[10];
    const float* enc_eb1  = (const float*)d_in[11];
    const float* enc_eW2  = (const float*)d_in[12];
    const float* enc_eb2  = (const float*)d_in[13];
    const float* mp_eW1   = (const float*)d_in[14];
    const float* mp_eb1   = (const float*)d_in[15];
    const float* mp_eW2   = (const float*)d_in[16];
    const float* mp_eb2   = (const float*)d_in[17];
    const float* mp_nW1   = (const float*)d_in[18];
    const float* mp_nb1   = (const float*)d_in[19];
    const float* mp_nW2   = (const float*)d_in[20];
    const float* mp_nb2   = (const float*)d_in[21];
    const float* dec_W1   = (const float*)d_in[22];
    const float* dec_b1   = (const float*)d_in[23];
    const float* dec_W2   = (const float*)d_in[24];
    const float* dec_b2   = (const float*)d_in[25];
    const float* dec_W3   = (const float*)d_in[26];
    const float* dec_b3   = (const float*)d_in[27];

    const int N = in_sizes[0] / 9;
    const int E = in_sizes[2] / 10;
    const int L = in_sizes[15] / 128;   // mp_eb1 is (L,128)
    const int H = 128;

    const int* src = eidx;
    const int* dst = eidx + E;

    const size_t nh = (size_t)N * H;
    const size_t eh = (size_t)E * H;

    const int nblk    = (N + TILE - 1) / TILE;
    const int eblk    = (E + TILE - 1) / TILE;
    const int nblk128 = (N + 127) / 128;
    const int eblk128 = (E + 127) / 128;

    // ---------------- tier 3 workspace layout ----------------
    char* p = (char*)d_ws;
    float* h      = (float*)p;                 p += nh * 4;
    float* agg    = (float*)p;                 p += nh * 4;
    u16*   h_bf   = (u16*)p;                   p += nh * 2;
    u16*   e_bf3  = (u16*)p;                   p += eh * 2;
    u16*   W1t_e  = (u16*)p;                   p += (size_t)L * 128 * 384 * 2;
    u16*   W2t_e  = (u16*)p;                   p += (size_t)L * 128 * 128 * 2;
    u16*   W1t_n  = (u16*)p;                   p += (size_t)L * 128 * 256 * 2;
    u16*   W2t_n  = (u16*)p;                   p += (size_t)L * 128 * 128 * 2;
    u16*   W1t_ee = (u16*)p;                   p += (size_t)128 * 16 * 2;
    u16*   W2t_ee = (u16*)p;                   p += (size_t)128 * 128 * 2;
    int*   cnt    = (int*)p;                   p += (size_t)N * 4;
    int*   row_ptr= (int*)p;                   p += (size_t)(N + 1) * 4;
    int*   fill   = (int*)p;                   p += (size_t)N * 4;
    int*   src_s  = (int*)p;                   p += (size_t)E * 4;
    int*   dst_s  = (int*)p;                   p += (size_t)E * 4;
    int*   permE  = (int*)p;                   p += (size_t)E * 4;
    const size_t need3 = (size_t)(p - (char*)d_ws);

    // tier-2 layout (round-3 compatible)
    u16* h_bf2 = (u16*)((float*)d_ws + 2 * nh);
    u16* e_bf2 = h_bf2 + nh;
    u16* W1t2  = e_bf2 + eh;
    u16* W2t2  = W1t2 + (size_t)L * 128 * 384;
    const size_t need2 = 2 * nh * 4 + nh * 2 + eh * 2 +
                         (size_t)L * (128 * 384 + 128 * 128) * 2;
    const size_t need1 = 2 * nh * 4 + eh * 2;

    const int tier = (ws_size >= need3) ? 3 :
                     (ws_size >= need2) ? 2 :
                     (ws_size >= need1) ? 1 : 0;

    if (tier == 3) {
        // weight prep
        wt_stacked_kernel<<<(int)(((size_t)L*128*384 + 255)/256), 256, 0, stream>>>(
            mp_eW1, W1t_e, L, 384, 384, 128);
        wt_stacked_kernel<<<(int)(((size_t)L*128*128 + 255)/256), 256, 0, stream>>>(
            mp_eW2, W2t_e, L, 128, 128, 128);
        wt_stacked_kernel<<<(int)(((size_t)L*128*256 + 255)/256), 256, 0, stream>>>(
            mp_nW1, W1t_n, L, 256, 256, 128);
        wt_stacked_kernel<<<(int)(((size_t)L*128*128 + 255)/256), 256, 0, stream>>>(
            mp_nW2, W2t_n, L, 128, 128, 128);
        wt_stacked_kernel<<<(128*16 + 255)/256, 256, 0, stream>>>(
            enc_eW1, W1t_ee, 1, 10, 16, 128);
        wt_stacked_kernel<<<(128*128 + 255)/256, 256, 0, stream>>>(
            enc_eW2, W2t_ee, 1, 128, 128, 128);
        // counting sort by dst
        hipMemsetAsync(cnt, 0, (size_t)N * 4, stream);
        hipMemsetAsync(fill, 0, (size_t)N * 4, stream);
        hist_kernel<<<(E + 255)/256, 256, 0, stream>>>(dst, cnt, E);
        scan_kernel<<<1, 1024, 0, stream>>>(cnt, row_ptr, N);
        scatter_kernel<<<(E + 255)/256, 256, 0, stream>>>(
            src, dst, row_ptr, fill, src_s, dst_s, permE, E);
        // encoders
        node_enc_kernel<<<nblk, 256, 0, stream>>>(x, coords, enc_nW1, enc_nb1,
                                                  enc_nW2, enc_nb2, h, h_bf, N);
        edge_enc_mfma_kernel<<<eblk128, 256, 0, stream>>>(
            ea, W1t_ee, enc_eb1, W2t_ee, enc_eb2, e_bf3, E);
        // layers
        for (int l = 0; l < L; ++l) {
            hipMemsetAsync(agg, 0, nh * 4, stream);
            edge_mp_sorted_kernel<<<eblk128, 256, 0, stream>>>(
                h_bf, e_bf3, src_s, dst_s, permE,
                W1t_e + (size_t)l * 128 * 384, mp_eb1 + (size_t)l * H,
                W2t_e + (size_t)l * 128 * 128, mp_eb2 + (size_t)l * H,
                agg, E);
            node_mp_mfma_kernel<<<nblk128, 256, 0, stream>>>(
                h, h_bf, agg,
                W1t_n + (size_t)l * 128 * 256, mp_nb1 + (size_t)l * H,
                W2t_n + (size_t)l * 128 * 128, mp_nb2 + (size_t)l * H,
                N);
        }
        decoder_kernel<<<nblk, 256, 0, stream>>>(h, dec_W1, dec_b1, dec_W2, dec_b2,
                                                 dec_W3, dec_b3, bc_disp, bc_rot,
                                                 (float*)d_out, N);
        return;
    }

    // ---------------- tiers 0-2 (previous fallbacks) ----------------
    node_enc_kernel<<<nblk, 256, 0, stream>>>(x, coords, enc_nW1, enc_nb1,
                                              enc_nW2, enc_nb2, h,
                                              tier == 2 ? h_bf2 : (u16*)nullptr, N);
    if (tier >= 1) {
        u16* e_t1 = (tier == 2) ? e_bf2 : (u16*)((float*)d_ws + 2 * nh);
        edge_enc_bf16_kernel<<<eblk, 256, 0, stream>>>(ea, enc_eW1, enc_eb1,
                                                       enc_eW2, enc_eb2, e_t1, E);
        if (tier == 2) {
            wt_stacked_kernel<<<(int)(((size_t)L*128*384 + 255)/256), 256, 0, stream>>>(
                mp_eW1, W1t2, L, 384, 384, 128);
            wt_stacked_kernel<<<(int)(((size_t)L*128*128 + 255)/256), 256, 0, stream>>>(
                mp_eW2, W2t2, L, 128, 128, 128);
        }
    }
    for (int l = 0; l < L; ++l) {
        hipMemsetAsync(agg, 0, nh * 4, stream);
        if (tier == 2) {
            edge_mp_mfma_kernel<<<eblk128, 256, 0, stream>>>(
                h_bf2, e_bf2, src, dst,
                W1t2 + (size_t)l * 128 * 384, mp_eb1 + (size_t)l * H,
                W2t2 + (size_t)l * 128 * 128, mp_eb2 + (size_t)l * H,
                agg, E);
        } else if (tier == 1) {
            edge_mp_a_kernel<<<eblk, 256, 0, stream>>>(
                h, (u16*)((float*)d_ws + 2 * nh), src, dst,
                mp_eW1 + (size_t)l * 3 * H * H, mp_eb1 + (size_t)l * H,
                mp_eW2 + (size_t)l * H * H,     mp_eb2 + (size_t)l * H,
                agg, E);
        } else {
            edge_mp_b_kernel<<<eblk, 256, 0, stream>>>(
                h, ea, src, dst,
                enc_eW1, enc_eb1, enc_eW2, enc_eb2,
                mp_eW1 + (size_t)l * 3 * H * H, mp_eb1 + (size_t)l * H,
                mp_eW2 + (size_t)l * H * H,     mp_eb2 + (size_t)l * H,
                agg, E);
        }
        node_mp_kernel<<<nblk, 256, 0, stream>>>(
            h, tier == 2 ? h_bf2 : (u16*)nullptr, agg,
            mp_nW1 + (size_t)l * 2 * H * H, mp_nb1 + (size_t)l * H,
            mp_nW2 + (size_t)l * H * H,     mp_nb2 + (size_t)l * H,
            N);
    }
    decoder_kernel<<<nblk, 256, 0, stream>>>(h, dec_W1, dec_b1, dec_W2, dec_b2,
                                             dec_W3, dec_b3, bc_disp, bc_rot,
                                             (float*)d_out, N);
}